// Round 9
// baseline (77.864 us; speedup 1.0000x reference)
//
#include <hip/hip_runtime.h>
#include <math.h>
#include <stdint.h>

#define NB 128
#define NS 300   // pred slots (columns)
#define NG 100   // gt slots (max rows)
#define NP 10    // params per stroke
#define NSLOT 5  // ceil(NS/64)
#define NCROW 16 // LDS row-cache slots (direct-mapped, row & 15)

// ws layout: [0,64): acc doubles; [1024, ...): cost matrix C
#define WS_ACC 0
#define WS_C   1024
#define WS_NEEDED (WS_C + (size_t)NB * NG * NS * 8)

#define GET_SLOT(arr, slot, out) do { switch (slot) { \
  case 0: out = arr[0]; break; case 1: out = arr[1]; break; \
  case 2: out = arr[2]; break; case 3: out = arr[3]; break; \
  default: out = arr[4]; break; } } while (0)
#define SET_SLOT(arr, slot, val) do { switch (slot) { \
  case 0: arr[0] = val; break; case 1: arr[1] = val; break; \
  case 2: arr[2] = val; break; case 3: arr[3] = val; break; \
  default: arr[4] = val; break; } } while (0)

__device__ __forceinline__ double wave_sum(double v) {
  #pragma unroll
  for (int off = 32; off > 0; off >>= 1) v += __shfl_xor(v, off);
  return v;
}

// ---- order-preserving f64 <-> u64 key ----
__device__ __forceinline__ uint64_t pack_key(double d) {
  const uint64_t b = (uint64_t)__double_as_longlong(d);
  return (b >> 63) ? ~b : (b | 0x8000000000000000ull);
}
__device__ __forceinline__ double unpack_key(uint64_t k) {
  const uint64_t b = (k >> 63) ? (k & 0x7fffffffffffffffull) : ~k;
  return __longlong_as_double((long long)b);
}

__device__ __forceinline__ double rl_f64(double v, int src) {
  const uint64_t b = (uint64_t)__double_as_longlong(v);
  const int lo = __builtin_amdgcn_readlane((int)(uint32_t)b, src);
  const int hi = __builtin_amdgcn_readlane((int)(uint32_t)(b >> 32), src);
  return __longlong_as_double((long long)(((uint64_t)(uint32_t)hi << 32) |
                                          (uint32_t)lo));
}

template <int CTRL>
__device__ __forceinline__ uint64_t dpp_u64_or_max(uint64_t x) {
  const int lo = (int)(uint32_t)x;
  const int hi = (int)(uint32_t)(x >> 32);
  const int lo2 = __builtin_amdgcn_update_dpp(-1, lo, CTRL, 0xF, 0xF, false);
  const int hi2 = __builtin_amdgcn_update_dpp(-1, hi, CTRL, 0xF, 0xF, false);
  return ((uint64_t)(uint32_t)hi2 << 32) | (uint32_t)lo2;
}

__device__ __forceinline__ void wave_argmin(uint64_t key, int bestj,
                                            double& minVal, int& jstar) {
  uint64_t k = key;
  { const uint64_t o = dpp_u64_or_max<0x111>(k); if (o < k) k = o; }
  { const uint64_t o = dpp_u64_or_max<0x112>(k); if (o < k) k = o; }
  { const uint64_t o = dpp_u64_or_max<0x114>(k); if (o < k) k = o; }
  { const uint64_t o = dpp_u64_or_max<0x118>(k); if (o < k) k = o; }
  { const uint64_t o = dpp_u64_or_max<0x142>(k); if (o < k) k = o; }
  { const uint64_t o = dpp_u64_or_max<0x143>(k); if (o < k) k = o; }
  const uint32_t mlo = (uint32_t)__builtin_amdgcn_readlane((int)(uint32_t)k, 63);
  const uint32_t mhi = (uint32_t)__builtin_amdgcn_readlane((int)(uint32_t)(k >> 32), 63);
  const uint64_t minkey = ((uint64_t)mhi << 32) | mlo;
  const unsigned long long winners = __ballot(key == minkey);
  const int src = __ffsll(winners) - 1;
  jstar = __builtin_amdgcn_readlane(bestj, src);
  minVal = unpack_key(minkey);
}

// ---- fast 32-bit-high-word DPP argmin with exact tie resolution ----
__device__ __forceinline__ int argmin32_src(double bestv) {
  const uint64_t key = pack_key(bestv);
  const uint32_t hi = (uint32_t)(key >> 32);
  int x = (int)hi;
  { const int o = __builtin_amdgcn_update_dpp(-1, x, 0x111, 0xF, 0xF, false);
    x = ((uint32_t)o < (uint32_t)x) ? o : x; }
  { const int o = __builtin_amdgcn_update_dpp(-1, x, 0x112, 0xF, 0xF, false);
    x = ((uint32_t)o < (uint32_t)x) ? o : x; }
  { const int o = __builtin_amdgcn_update_dpp(-1, x, 0x114, 0xF, 0xF, false);
    x = ((uint32_t)o < (uint32_t)x) ? o : x; }
  { const int o = __builtin_amdgcn_update_dpp(-1, x, 0x118, 0xF, 0xF, false);
    x = ((uint32_t)o < (uint32_t)x) ? o : x; }
  { const int o = __builtin_amdgcn_update_dpp(-1, x, 0x142, 0xF, 0xF, false);
    x = ((uint32_t)o < (uint32_t)x) ? o : x; }
  { const int o = __builtin_amdgcn_update_dpp(-1, x, 0x143, 0xF, 0xF, false);
    x = ((uint32_t)o < (uint32_t)x) ? o : x; }
  const uint32_t minhi = (uint32_t)__builtin_amdgcn_readlane(x, 63);
  unsigned long long cand = __ballot(hi == minhi);
  int src = __ffsll(cand) - 1;
  if (__popcll(cand) > 1) {
    uint64_t bk = ~0ull; int bs = src;
    while (cand) {
      const int l = __ffsll(cand) - 1; cand &= cand - 1;
      const uint32_t klo = (uint32_t)__builtin_amdgcn_readlane((int)(uint32_t)key, l);
      const uint32_t khi = (uint32_t)__builtin_amdgcn_readlane((int)(uint32_t)(key >> 32), l);
      const uint64_t kk = ((uint64_t)khi << 32) | klo;
      if (kk < bk) { bk = kk; bs = l; }
    }
    src = bs;
  }
  return src;
}

// ---------------------------------------------------------------------------
// Fused kernel: one block = one batch, 4 waves.
// Phase A (4 waves): LDS staging, f32 softmax, compaction, cost rows -> global
//   C + register DPP rowmin -> LDS, baseCE partials.
// Phase B (wave 0, barrier-free): greedy tight claims + SAP with 32-bit DPP
//   argmin, speculative row prefetch, direct-mapped LDS row cache.
// Epilogue (4 waves): matched regression + CE (computed from logits directly).
// ---------------------------------------------------------------------------
__global__ __launch_bounds__(256) void detr_fused_kernel(
    const float* __restrict__ strokes,
    const float* __restrict__ logits,
    const float* __restrict__ tparams,
    const int*   __restrict__ tlabels,
    double*      __restrict__ C,
    double*      __restrict__ acc)
{
  __shared__ float  sS[NS * NP];        // 12000
  __shared__ float  sP[NS * 3];         //  3600
  __shared__ int    s_valid[NG];
  __shared__ int    s_vlab[NG];
  __shared__ double s_rowminL[NG];
  __shared__ int    s_rowargL[NG];
  __shared__ int    s_claimC[NS];
  __shared__ int    s_r4cL[NS];
  __shared__ double s_short[NS];
  __shared__ int    s_col4row[NG];
  __shared__ double s_crow[NCROW * NS]; // 38400 row cache
  __shared__ int    s_ctag[NCROW];
  __shared__ double s_bp[4];
  __shared__ double s_baseCE;
  __shared__ int    s_nv;

  const int b    = blockIdx.x;
  const int tid  = threadIdx.x;
  const int wv   = tid >> 6;
  const int lane = tid & 63;
  const double INF = (double)INFINITY;

  // ---- Phase A: staging + softmax + init ----
  for (int idx = tid; idx < NS * NP; idx += 256)
    sS[idx] = strokes[b * NS * NP + idx];
  for (int j = tid; j < NS; j += 256) {
    const float x0 = logits[(b * NS + j) * 3 + 0];
    const float x1 = logits[(b * NS + j) * 3 + 1];
    const float x2 = logits[(b * NS + j) * 3 + 2];
    const float m  = fmaxf(x0, fmaxf(x1, x2));
    const float e0 = expf(x0 - m), e1 = expf(x1 - m), e2 = expf(x2 - m);
    const float s  = e0 + e1 + e2;
    sP[j * 3 + 0] = e0 / s;
    sP[j * 3 + 1] = e1 / s;
    sP[j * 3 + 2] = e2 / s;
    s_claimC[j] = 0x7fffffff;
    s_r4cL[j]   = -1;
  }
  if (tid < NCROW) s_ctag[tid] = -1;

  // stable compaction via ballots (wave 0)
  if (tid < 64) {
    const unsigned long long below = (1ull << lane) - 1ull;
    const int lb1 = tlabels[b * NG + lane];
    const bool in2 = lane < (NG - 64);
    const int lb2 = in2 ? tlabels[b * NG + 64 + lane] : 0;
    const unsigned long long m1 = __ballot(lb1 > 0);
    const unsigned long long m2 = __ballot(in2 && lb2 > 0);
    const int c1 = __popcll(m1);
    if (lb1 > 0) {
      const int p = __popcll(m1 & below);
      s_valid[p] = lane; s_vlab[p] = lb1;
    }
    if (in2 && lb2 > 0) {
      const int p = c1 + __popcll(m2 & below);
      s_valid[p] = 64 + lane; s_vlab[p] = lb2;
    }
    if (lane == 0) s_nv = c1 + __popcll(m2);
  }
  __syncthreads();
  const int nv = s_nv;
  for (int i = tid; i < nv; i += 256) s_col4row[i] = -1;

  // baseCE partials (all threads)
  {
    double bsum = 0.0;
    for (int s = tid; s < NS; s += 256) {
      const double x0 = (double)logits[(b * NS + s) * 3 + 0];
      const double x1 = (double)logits[(b * NS + s) * 3 + 1];
      const double x2 = (double)logits[(b * NS + s) * 3 + 2];
      const double m   = fmax(x0, fmax(x1, x2));
      const double lse = log(exp(x0 - m) + exp(x1 - m) + exp(x2 - m));
      bsum += 0.1 * (-(x0 - m - lse));
    }
    bsum = wave_sum(bsum);
    if (lane == 0) s_bp[wv] = bsum;
  }

  // cost rows: wave wv handles rows wv, wv+4, ... ; fused register rowmin
  const int vmask = (lane < NS - 4 * 64) ? 0x1F : 0x0F;
  for (int i = wv; i < nv; i += 4) {
    const int g   = s_valid[i];
    const int cls = s_vlab[i];
    double vt[NP];
    #pragma unroll
    for (int k = 0; k < NP; ++k)
      vt[k] = (double)tparams[((size_t)b * NG + g) * NP + k];
    double cc[NSLOT];
    #pragma unroll
    for (int s = 0; s < NSLOT; ++s) {
      if ((vmask >> s) & 1) {
        const int j = lane + 64 * s;
        const double p = (double)sP[j * 3 + cls];
        double a[NP];
        #pragma unroll
        for (int k = 0; k < NP; ++k)
          a[k] = fabs((double)sS[j * NP + k] - vt[k]);
        const double coord = ((a[0] + a[1]) + (a[2] + a[3])) +
                             ((a[4] + a[5]) + (a[6] + a[7]));
        const double c = -p + 5.0 * coord + 2.0 * (a[8] + a[9]) +
                         2.0 * (a[0] + a[1]);
        C[((size_t)b * NG + i) * NS + j] = c;
        cc[s] = c;
      } else cc[s] = INF;
    }
    double bestv = INF;
    int    bestj = 0x7fffffff;
    #pragma unroll
    for (int s = 0; s < NSLOT; ++s)
      if (((vmask >> s) & 1) && cc[s] < bestv) { bestv = cc[s]; bestj = lane + 64 * s; }
    double mv; int js;
    wave_argmin(pack_key(bestv), bestj, mv, js);
    if (lane == 0) { s_rowminL[i] = mv; s_rowargL[i] = js; }
  }
  __syncthreads();
  if (tid == 0) s_baseCE = (s_bp[0] + s_bp[1]) + (s_bp[2] + s_bp[3]);

  // ---- Phase B: wave 0 only, barrier-free ----
  if (wv == 0 && nv > 0) {
    const double* Cb = C + (size_t)b * NG * NS;

    double rm0 = 0.0, rm1 = 0.0;
    int    ra0 = -1,  ra1 = -1;
    if (lane < nv)      { rm0 = s_rowminL[lane];      ra0 = s_rowargL[lane]; }
    if (lane + 64 < nv) { rm1 = s_rowminL[lane + 64]; ra1 = s_rowargL[lane + 64]; }

    if (lane < nv)      atomicMin(&s_claimC[ra0], lane);
    if (lane + 64 < nv) atomicMin(&s_claimC[ra1], lane + 64);
    __builtin_amdgcn_wave_barrier();
    if (lane < nv && s_claimC[ra0] == lane) {
      s_r4cL[ra0] = lane; s_col4row[lane] = ra0;
    }
    if (lane + 64 < nv && s_claimC[ra1] == lane + 64) {
      s_r4cL[ra1] = lane + 64; s_col4row[lane + 64] = ra1;
    }
    __builtin_amdgcn_wave_barrier();

    int r4c[NSLOT];
    #pragma unroll
    for (int s = 0; s < NSLOT; ++s)
      r4c[s] = ((vmask >> s) & 1) ? s_r4cL[lane + 64 * s] : -1;
    double vv[NSLOT];
    #pragma unroll
    for (int s = 0; s < NSLOT; ++s) vv[s] = 0.0;

    double u0 = rm0, u1 = rm1;

    unsigned long long f0 = __ballot(lane < nv && s_col4row[lane] < 0);
    unsigned long long f1 = __ballot(lane + 64 < nv && s_col4row[lane + 64] < 0);

    int pf_row = -1;
    double pfv[NSLOT];
    #pragma unroll
    for (int s = 0; s < NSLOT; ++s) pfv[s] = 0.0;

#define PRELOAD(ROW) do { \
      const double* Pr_ = Cb + (size_t)(ROW) * NS; \
      pfv[0] = Pr_[lane]; \
      pfv[1] = Pr_[lane + 64]; \
      pfv[2] = Pr_[lane + 128]; \
      pfv[3] = Pr_[lane + 192]; \
      if (lane < NS - 256) pfv[4] = Pr_[lane + 256]; \
    } while (0)

    {
      int n = -1;
      if (f0) n = __ffsll(f0) - 1; else if (f1) n = 64 + __ffsll(f1) - 1;
      if (n >= 0) { pf_row = n; PRELOAD(n); }
    }

    while (f0 | f1) {
      int cur;
      if (f0) { cur = __ffsll(f0) - 1; f0 &= f0 - 1; }
      else    { cur = 64 + __ffsll(f1) - 1; f1 &= f1 - 1; }

      double sh[NSLOT];
      int    pa[NSLOT];
      #pragma unroll
      for (int s = 0; s < NSLOT; ++s) { sh[s] = INF; pa[s] = -1; }
      int scm = 0;
      unsigned long long srm0 = 0ull, srm1 = 0ull;
      double minVal = 0.0;
      int i = cur;
      int sink = -1;

      while (sink == -1) {
        if (i < 64) srm0 |= (1ull << i); else srm1 |= (1ull << (i - 64));
        const double ucur = (i < 64) ? rl_f64(u0, i) : rl_f64(u1, i - 64);
        const double base = minVal - ucur;

        // row values: prefetch regs > LDS cache > global (+fill cache)
        const int cs = i & (NCROW - 1);
        const bool cached = (s_ctag[cs] == i);
        double cv[NSLOT];
        if (i == pf_row) {
          #pragma unroll
          for (int s = 0; s < NSLOT; ++s) cv[s] = pfv[s];
          if (!cached) {
            #pragma unroll
            for (int s = 0; s < NSLOT; ++s)
              if ((vmask >> s) & 1) s_crow[cs * NS + lane + 64 * s] = pfv[s];
            if (lane == 0) s_ctag[cs] = i;
          }
        } else if (cached) {
          #pragma unroll
          for (int s = 0; s < NSLOT; ++s)
            if ((vmask >> s) & 1) cv[s] = s_crow[cs * NS + lane + 64 * s];
        } else {
          const double* Gr = Cb + (size_t)i * NS;
          #pragma unroll
          for (int s = 0; s < NSLOT; ++s)
            if ((vmask >> s) & 1) cv[s] = Gr[lane + 64 * s];
          #pragma unroll
          for (int s = 0; s < NSLOT; ++s)
            if ((vmask >> s) & 1) s_crow[cs * NS + lane + 64 * s] = cv[s];
          if (lane == 0) s_ctag[cs] = i;
        }

        double bestv = INF;
        int    bestj = 0x7fffffff;
        #pragma unroll
        for (int s = 0; s < NSLOT; ++s) {
          if ((vmask >> s) & 1) {
            if (!((scm >> s) & 1)) {
              const double dd = base + cv[s] - vv[s];
              if (dd < sh[s]) { sh[s] = dd; pa[s] = i; }
              if (sh[s] < bestv) { bestv = sh[s]; bestj = lane + 64 * s; }
            }
          }
        }

        const int src = argmin32_src(bestv);
        const int jstar = __builtin_amdgcn_readlane(bestj, src);
        minVal = rl_f64(bestv, src);
        const int slot = jstar >> 6;
        const int jl   = jstar & 63;
        if (lane == jl) scm |= (1 << slot);

        int t;
        GET_SLOT(r4c, slot, t);
        const int rc = __builtin_amdgcn_readlane(t, jl);
        if (rc < 0) {
          sink = jstar;
        } else {
          i = rc;
          double b2 = INF;
          int    bj2 = 0x7fffffff;
          #pragma unroll
          for (int s = 0; s < NSLOT; ++s) {
            if ((vmask >> s) & 1) {
              if (!((scm >> s) & 1) && sh[s] < b2) {
                b2 = sh[s]; bj2 = lane + 64 * s;
              }
            }
          }
          const int src2 = argmin32_src(b2);
          const int j2 = __builtin_amdgcn_readlane(bj2, src2);
          int t2;
          GET_SLOT(r4c, (j2 >> 6), t2);
          const int rc2 = __builtin_amdgcn_readlane(t2, j2 & 63);
          if (rc2 >= 0 && rc2 != i && s_ctag[rc2 & (NCROW - 1)] != rc2) {
            pf_row = rc2; PRELOAD(rc2);
          } else pf_row = -1;
        }
      }

      #pragma unroll
      for (int s = 0; s < NSLOT; ++s)
        if ((vmask >> s) & 1) s_short[lane + 64 * s] = sh[s];
      __builtin_amdgcn_wave_barrier();

      if (((srm0 >> lane) & 1ull) && lane != cur)
        u0 += minVal - s_short[s_col4row[lane]];
      const int r2 = lane + 64;
      if (((srm1 >> lane) & 1ull) && r2 != cur)
        u1 += minVal - s_short[s_col4row[r2]];
      if (lane == cur) u0 += minVal;
      if (r2 == cur)   u1 += minVal;
      #pragma unroll
      for (int s = 0; s < NSLOT; ++s)
        if ((scm >> s) & 1) vv[s] -= minVal - sh[s];
      __builtin_amdgcn_wave_barrier();

      // augmenting-path flip
      int j = sink;
      while (true) {
        const int slot = j >> 6, src3 = j & 63;
        int t;
        GET_SLOT(pa, slot, t);
        const int i2 = __builtin_amdgcn_readlane(t, src3);
        if (lane == src3) SET_SLOT(r4c, slot, i2);
        const int nxt = s_col4row[i2];
        if (lane == 0) s_col4row[i2] = j;
        if (i2 == cur) break;
        j = nxt;
      }
      __builtin_amdgcn_wave_barrier();

      {
        int n = -1;
        if (f0) n = __ffsll(f0) - 1; else if (f1) n = 64 + __ffsll(f1) - 1;
        if (n >= 0) { pf_row = n; PRELOAD(n); }
      }
    }
#undef PRELOAD
  }
  __syncthreads();

  // ---- Epilogue (all 4 waves): regression + CE ----
  double l1 = 0.0, sl1 = 0.0, wd = 0.0, wnll = 0.0;
  for (int i = tid; i < nv; i += 256) {
    const int r = s_col4row[i];
    const int c = s_vlab[i];
    // CE delta for matched slot (same f64 formula as before)
    {
      const double x0 = (double)logits[(b * NS + r) * 3 + 0];
      const double x1 = (double)logits[(b * NS + r) * 3 + 1];
      const double x2 = (double)logits[(b * NS + r) * 3 + 2];
      const double m   = fmax(x0, fmax(x1, x2));
      const double lse = log(exp(x0 - m) + exp(x1 - m) + exp(x2 - m));
      const double nll0 = -(x0 - m - lse);
      const double nllc = -(((c == 1) ? x1 : x2) - m - lse);
      wnll += nllc - 0.1 * nll0;
    }
    const float* tp = tparams + ((size_t)b * NG + s_valid[i]) * NP;
    #pragma unroll
    for (int k = 0; k < 8; ++k) {
      const float d  = sS[r * NP + k] - tp[k];
      const float ad = fabsf(d);
      l1 += (double)ad;
      const float sm = (ad < 0.1f) ? (0.5f * ad * ad / 0.1f) : (ad - 0.05f);
      sl1 += (double)sm;
    }
    const float d8 = fabsf(sS[r * NP + 8] - tp[8]);
    const float d9 = fabsf(sS[r * NP + 9] - tp[9]);
    wd += (double)d8 + (double)d9;
  }
  l1 = wave_sum(l1); sl1 = wave_sum(sl1); wd = wave_sum(wd); wnll = wave_sum(wnll);
  if (lane == 0) {
    atomicAdd(&acc[0], wnll);
    atomicAdd(&acc[2], l1);
    atomicAdd(&acc[3], sl1);
    atomicAdd(&acc[4], wd);
  }
  if (tid == 0) {
    atomicAdd(&acc[0], s_baseCE);
    atomicAdd(&acc[1], 30.0 + 0.9 * (double)nv);
    atomicAdd(&acc[5], (double)nv);
  }
}

// ---------------------------------------------------------------------------
// Fallback (ws too small): round-0 monolithic kernel (proven, absmax 0.0).
// ---------------------------------------------------------------------------
__global__ __launch_bounds__(64) void detr_match_loss_kernel(
    const float* __restrict__ strokes,
    const float* __restrict__ logits,
    const float* __restrict__ tparams,
    const int*   __restrict__ tlabels,
    double*      __restrict__ acc)
{
  __shared__ float  s_strokes[NS * NP];
  __shared__ float  s_probs[NS * 3];
  __shared__ float  s_vt[NG * NP];
  __shared__ int    s_valid[NG];
  __shared__ int    s_vlab[NG];
  __shared__ double s_u[NG];
  __shared__ int    s_col4row[NG];
  __shared__ int    s_SRb[NG];
  __shared__ double s_shortest[NS];
  __shared__ double s_v[NS];
  __shared__ int    s_path[NS];
  __shared__ int    s_SC[NS];
  __shared__ int    s_row4col[NS];
  __shared__ int    s_tc[NS];
  __shared__ int    s_nv;

  const int b    = blockIdx.x;
  const int lane = threadIdx.x;

  for (int idx = lane; idx < NS * NP; idx += 64)
    s_strokes[idx] = strokes[b * NS * NP + idx];

  for (int j = lane; j < NS; j += 64) {
    const float x0 = logits[(b * NS + j) * 3 + 0];
    const float x1 = logits[(b * NS + j) * 3 + 1];
    const float x2 = logits[(b * NS + j) * 3 + 2];
    const float m  = fmaxf(x0, fmaxf(x1, x2));
    const float e0 = expf(x0 - m), e1 = expf(x1 - m), e2 = expf(x2 - m);
    const float s  = e0 + e1 + e2;
    s_probs[j * 3 + 0] = e0 / s;
    s_probs[j * 3 + 1] = e1 / s;
    s_probs[j * 3 + 2] = e2 / s;
    s_tc[j]      = 0;
    s_row4col[j] = -1;
    s_v[j]       = 0.0;
  }

  if (lane == 0) {
    int nv = 0;
    for (int g = 0; g < NG; ++g) {
      const int lb = tlabels[b * NG + g];
      if (lb > 0) { s_valid[nv] = g; s_vlab[nv] = lb; ++nv; }
    }
    s_nv = nv;
  }
  __syncthreads();
  const int nv = s_nv;

  for (int idx = lane; idx < nv * NP; idx += 64) {
    const int i = idx / NP, k = idx % NP;
    s_vt[idx] = tparams[(b * NG + s_valid[i]) * NP + k];
  }
  for (int i = lane; i < nv; i += 64) { s_u[i] = 0.0; s_col4row[i] = -1; }
  __syncthreads();

  if (nv > 0) {
    for (int cur = 0; cur < nv; ++cur) {
      for (int j = lane; j < NS; j += 64) {
        s_shortest[j] = 1e300;
        s_path[j]     = -1;
        s_SC[j]       = 0;
      }
      for (int r = lane; r < nv; r += 64) s_SRb[r] = 0;
      __syncthreads();

      double minVal = 0.0;
      int i = cur;
      int sink = -1;

      while (sink == -1) {
        if (lane == 0) s_SRb[i] = 1;
        const double ui  = s_u[i];
        const int    cls = s_vlab[i];
        double vtr[NP];
        #pragma unroll
        for (int k = 0; k < NP; ++k) vtr[k] = (double)s_vt[i * NP + k];
        const double base = minVal - ui;

        double bestv = 1e300;
        int    bestj = 0x7fffffff;

        for (int j = lane; j < NS; j += 64) {
          if (!s_SC[j]) {
            const double p = (double)s_probs[j * 3 + cls];
            double a[NP];
            #pragma unroll
            for (int k = 0; k < NP; ++k)
              a[k] = fabs((double)s_strokes[j * NP + k] - vtr[k]);
            const double coord = ((a[0] + a[1]) + (a[2] + a[3])) +
                                 ((a[4] + a[5]) + (a[6] + a[7]));
            const double c = -p + 5.0 * coord + 2.0 * (a[8] + a[9]) +
                             2.0 * (a[0] + a[1]);
            const double d = base + c - s_v[j];
            if (d < s_shortest[j]) { s_shortest[j] = d; s_path[j] = i; }
            const double sv = s_shortest[j];
            if (sv < bestv) { bestv = sv; bestj = j; }
          }
        }

        #pragma unroll
        for (int off = 32; off > 0; off >>= 1) {
          const double ov = __shfl_xor(bestv, off);
          const int    oj = __shfl_xor(bestj, off);
          if (ov < bestv || (ov == bestv && oj < bestj)) { bestv = ov; bestj = oj; }
        }
        minVal = bestv;
        const int jstar = bestj;
        if (lane == 0) s_SC[jstar] = 1;
        __syncthreads();
        const int rc = s_row4col[jstar];
        if (rc < 0) sink = jstar; else i = rc;
      }

      for (int r = lane; r < nv; r += 64)
        if (s_SRb[r] && r != cur)
          s_u[r] += minVal - s_shortest[s_col4row[r]];
      if (lane == 0) s_u[cur] += minVal;
      for (int j = lane; j < NS; j += 64)
        if (s_SC[j]) s_v[j] -= minVal - s_shortest[j];
      __syncthreads();

      if (lane == 0) {
        int j = sink;
        while (true) {
          const int i2 = s_path[j];
          s_row4col[j] = i2;
          const int nxt = s_col4row[i2];
          s_col4row[i2] = j;
          if (i2 == cur) break;
          j = nxt;
        }
      }
      __syncthreads();
    }

    double l1 = 0.0, sl1 = 0.0, wid = 0.0;
    for (int i = lane; i < nv; i += 64) {
      const int r = s_col4row[i];
      s_tc[r] = s_vlab[i];
      #pragma unroll
      for (int k = 0; k < 8; ++k) {
        const float d  = s_strokes[r * NP + k] - s_vt[i * NP + k];
        const float ad = fabsf(d);
        l1 += (double)ad;
        const float s = (ad < 0.1f) ? (0.5f * ad * ad / 0.1f) : (ad - 0.05f);
        sl1 += (double)s;
      }
      const float d8 = fabsf(s_strokes[r * NP + 8] - s_vt[i * NP + 8]);
      const float d9 = fabsf(s_strokes[r * NP + 9] - s_vt[i * NP + 9]);
      wid += (double)d8 + (double)d9;
    }
    l1 = wave_sum(l1); sl1 = wave_sum(sl1); wid = wave_sum(wid);
    if (lane == 0) {
      atomicAdd(&acc[2], l1);
      atomicAdd(&acc[3], sl1);
      atomicAdd(&acc[4], wid);
      atomicAdd(&acc[5], (double)nv);
    }
  }
  __syncthreads();

  double wnll = 0.0, wsum = 0.0;
  for (int s = lane; s < NS; s += 64) {
    const int tc = s_tc[s];
    const double x0 = (double)logits[(b * NS + s) * 3 + 0];
    const double x1 = (double)logits[(b * NS + s) * 3 + 1];
    const double x2 = (double)logits[(b * NS + s) * 3 + 2];
    const double m   = fmax(x0, fmax(x1, x2));
    const double lse = log(exp(x0 - m) + exp(x1 - m) + exp(x2 - m));
    const double xt  = (tc == 0) ? x0 : ((tc == 1) ? x1 : x2);
    const double nll = -(xt - m - lse);
    const double w   = (tc == 0) ? 0.1 : 1.0;
    wnll += w * nll;
    wsum += w;
  }
  wnll = wave_sum(wnll); wsum = wave_sum(wsum);
  if (lane == 0) {
    atomicAdd(&acc[0], wnll);
    atomicAdd(&acc[1], wsum);
  }
}

__global__ void detr_finalize_kernel(const double* __restrict__ acc,
                                     float* __restrict__ out) {
  const double loss_ce = acc[0] / acc[1];
  const double denom   = fmax(acc[5], 1.0);
  const double loss = 1.0 * loss_ce
                    + 5.0 * (acc[2] + acc[3]) / denom
                    + 2.0 * acc[4] / denom;
  out[0] = (float)loss;
}

extern "C" void kernel_launch(void* const* d_in, const int* in_sizes, int n_in,
                              void* d_out, int out_size, void* d_ws, size_t ws_size,
                              hipStream_t stream) {
  const float* strokes = (const float*)d_in[0];
  const float* logits  = (const float*)d_in[1];
  const float* tparams = (const float*)d_in[2];
  const int*   tlabels = (const int*)d_in[3];
  char* ws = (char*)d_ws;
  double* acc = (double*)(ws + WS_ACC);

  hipMemsetAsync(d_ws, 0, 64, stream);

  if (ws_size >= WS_NEEDED) {
    double* C = (double*)(ws + WS_C);
    detr_fused_kernel<<<NB, 256, 0, stream>>>(strokes, logits, tparams,
                                              tlabels, C, acc);
  } else {
    detr_match_loss_kernel<<<NB, 64, 0, stream>>>(strokes, logits, tparams,
                                                  tlabels, acc);
  }
  detr_finalize_kernel<<<1, 1, 0, stream>>>(acc, (float*)d_out);
}

// Round 10
// 71.865 us; speedup vs baseline: 1.0835x; 1.0835x over previous
//
#include <hip/hip_runtime.h>
#include <math.h>
#include <stdint.h>

#define NB 128
#define NS 300   // pred slots (columns)
#define NG 100   // gt slots (max rows)
#define NP 10    // params per stroke
#define NSLOT 5  // ceil(NS/64)
#define NCROW 32 // LDS row-cache slots (direct-mapped, row & 31)

// ws layout (all 8-aligned):
#define WS_ACC     0                         // 6 doubles + counter @48 (64 B)
#define WS_ROWMIN  1024                      // NB*NG*8 = 102400
#define WS_ROWARG  103424                    // NB*NG*4 = 51200
#define WS_DCE     154624                    // NB*NS*2*8 = 614400
#define WS_BASECE  769024                    // NB*8 (pad to 1024)
#define WS_C       770048                    // NB*NG*NS*8 = 30720000
#define WS_NEEDED  (WS_C + (size_t)NB * NG * NS * 8)

#define GET_SLOT(arr, slot, out) do { switch (slot) { \
  case 0: out = arr[0]; break; case 1: out = arr[1]; break; \
  case 2: out = arr[2]; break; case 3: out = arr[3]; break; \
  default: out = arr[4]; break; } } while (0)
#define SET_SLOT(arr, slot, val) do { switch (slot) { \
  case 0: arr[0] = val; break; case 1: arr[1] = val; break; \
  case 2: arr[2] = val; break; case 3: arr[3] = val; break; \
  default: arr[4] = val; break; } } while (0)

__device__ __forceinline__ double wave_sum(double v) {
  #pragma unroll
  for (int off = 32; off > 0; off >>= 1) v += __shfl_xor(v, off);
  return v;
}

// ---- order-preserving f64 <-> u64 key ----
__device__ __forceinline__ uint64_t pack_key(double d) {
  const uint64_t b = (uint64_t)__double_as_longlong(d);
  return (b >> 63) ? ~b : (b | 0x8000000000000000ull);
}
__device__ __forceinline__ double unpack_key(uint64_t k) {
  const uint64_t b = (k >> 63) ? (k & 0x7fffffffffffffffull) : ~k;
  return __longlong_as_double((long long)b);
}

__device__ __forceinline__ double rl_f64(double v, int src) {
  const uint64_t b = (uint64_t)__double_as_longlong(v);
  const int lo = __builtin_amdgcn_readlane((int)(uint32_t)b, src);
  const int hi = __builtin_amdgcn_readlane((int)(uint32_t)(b >> 32), src);
  return __longlong_as_double((long long)(((uint64_t)(uint32_t)hi << 32) |
                                          (uint32_t)lo));
}

template <int CTRL>
__device__ __forceinline__ uint64_t dpp_u64_or_max(uint64_t x) {
  const int lo = (int)(uint32_t)x;
  const int hi = (int)(uint32_t)(x >> 32);
  const int lo2 = __builtin_amdgcn_update_dpp(-1, lo, CTRL, 0xF, 0xF, false);
  const int hi2 = __builtin_amdgcn_update_dpp(-1, hi, CTRL, 0xF, 0xF, false);
  return ((uint64_t)(uint32_t)hi2 << 32) | (uint32_t)lo2;
}

__device__ __forceinline__ void wave_argmin(uint64_t key, int bestj,
                                            double& minVal, int& jstar) {
  uint64_t k = key;
  { const uint64_t o = dpp_u64_or_max<0x111>(k); if (o < k) k = o; }
  { const uint64_t o = dpp_u64_or_max<0x112>(k); if (o < k) k = o; }
  { const uint64_t o = dpp_u64_or_max<0x114>(k); if (o < k) k = o; }
  { const uint64_t o = dpp_u64_or_max<0x118>(k); if (o < k) k = o; }
  { const uint64_t o = dpp_u64_or_max<0x142>(k); if (o < k) k = o; }
  { const uint64_t o = dpp_u64_or_max<0x143>(k); if (o < k) k = o; }
  const uint32_t mlo = (uint32_t)__builtin_amdgcn_readlane((int)(uint32_t)k, 63);
  const uint32_t mhi = (uint32_t)__builtin_amdgcn_readlane((int)(uint32_t)(k >> 32), 63);
  const uint64_t minkey = ((uint64_t)mhi << 32) | mlo;
  const unsigned long long winners = __ballot(key == minkey);
  const int src = __ffsll(winners) - 1;
  jstar = __builtin_amdgcn_readlane(bestj, src);
  minVal = unpack_key(minkey);
}

// ---- fast 32-bit-high-word DPP argmin with exact tie resolution ----
__device__ __forceinline__ int argmin32_src(double bestv) {
  const uint64_t key = pack_key(bestv);
  const uint32_t hi = (uint32_t)(key >> 32);
  int x = (int)hi;
  { const int o = __builtin_amdgcn_update_dpp(-1, x, 0x111, 0xF, 0xF, false);
    x = ((uint32_t)o < (uint32_t)x) ? o : x; }
  { const int o = __builtin_amdgcn_update_dpp(-1, x, 0x112, 0xF, 0xF, false);
    x = ((uint32_t)o < (uint32_t)x) ? o : x; }
  { const int o = __builtin_amdgcn_update_dpp(-1, x, 0x114, 0xF, 0xF, false);
    x = ((uint32_t)o < (uint32_t)x) ? o : x; }
  { const int o = __builtin_amdgcn_update_dpp(-1, x, 0x118, 0xF, 0xF, false);
    x = ((uint32_t)o < (uint32_t)x) ? o : x; }
  { const int o = __builtin_amdgcn_update_dpp(-1, x, 0x142, 0xF, 0xF, false);
    x = ((uint32_t)o < (uint32_t)x) ? o : x; }
  { const int o = __builtin_amdgcn_update_dpp(-1, x, 0x143, 0xF, 0xF, false);
    x = ((uint32_t)o < (uint32_t)x) ? o : x; }
  const uint32_t minhi = (uint32_t)__builtin_amdgcn_readlane(x, 63);
  unsigned long long cand = __ballot(hi == minhi);
  int src = __ffsll(cand) - 1;
  if (__popcll(cand) > 1) {
    uint64_t bk = ~0ull; int bs = src;
    while (cand) {
      const int l = __ffsll(cand) - 1; cand &= cand - 1;
      const uint32_t klo = (uint32_t)__builtin_amdgcn_readlane((int)(uint32_t)key, l);
      const uint32_t khi = (uint32_t)__builtin_amdgcn_readlane((int)(uint32_t)(key >> 32), l);
      const uint64_t kk = ((uint64_t)khi << 32) | klo;
      if (kk < bk) { bk = kk; bs = l; }
    }
    src = bs;
  }
  return src;
}

// ---------------------------------------------------------------------------
// Kernel B: cost matrix C (f64, bitwise == numpy) + fused row minima + CE
// decomposition (cb==0) + acc/counter zero-init (block 0,0).
// ---------------------------------------------------------------------------
__global__ __launch_bounds__(256) void detr_cost_kernel(
    const float* __restrict__ strokes,
    const float* __restrict__ logits,
    const float* __restrict__ tparams,
    const int*   __restrict__ tlabels,
    double*      __restrict__ C,
    double*      __restrict__ dce,
    double*      __restrict__ baseCE,
    double*      __restrict__ rowmin,
    int*         __restrict__ rowarg,
    double*      __restrict__ acc)
{
  __shared__ float  sS[NS * NP];
  __shared__ float  sP[NS * 3];
  __shared__ float  sVT[10 * NP];
  __shared__ int    sCls[10];
  __shared__ int    s_valid[NG];
  __shared__ int    s_vlab[NG];
  __shared__ int    s_nv;
  __shared__ double s_bp[4];
  __shared__ double sC[10 * NS];

  const int b   = blockIdx.x;
  const int cb  = blockIdx.y;
  const int tid = threadIdx.x;

  if (b == 0 && cb == 0 && tid < 8)
    acc[tid] = 0.0;   // zeroes 6 accumulators + the completion counter @48

  for (int idx = tid; idx < NS * NP; idx += 256)
    sS[idx] = strokes[b * NS * NP + idx];

  for (int j = tid; j < NS; j += 256) {
    const float x0 = logits[(b * NS + j) * 3 + 0];
    const float x1 = logits[(b * NS + j) * 3 + 1];
    const float x2 = logits[(b * NS + j) * 3 + 2];
    const float m  = fmaxf(x0, fmaxf(x1, x2));
    const float e0 = expf(x0 - m), e1 = expf(x1 - m), e2 = expf(x2 - m);
    const float s  = e0 + e1 + e2;
    sP[j * 3 + 0] = e0 / s;
    sP[j * 3 + 1] = e1 / s;
    sP[j * 3 + 2] = e2 / s;
  }

  if (tid < 64) {
    const unsigned long long below = (1ull << tid) - 1ull;
    const int lb1 = tlabels[b * NG + tid];
    const bool in2 = tid < (NG - 64);
    const int lb2 = in2 ? tlabels[b * NG + 64 + tid] : 0;
    const unsigned long long m1 = __ballot(lb1 > 0);
    const unsigned long long m2 = __ballot(in2 && lb2 > 0);
    const int c1 = __popcll(m1);
    if (lb1 > 0) {
      const int p = __popcll(m1 & below);
      s_valid[p] = tid; s_vlab[p] = lb1;
    }
    if (in2 && lb2 > 0) {
      const int p = c1 + __popcll(m2 & below);
      s_valid[p] = 64 + tid; s_vlab[p] = lb2;
    }
    if (tid == 0) s_nv = c1 + __popcll(m2);
  }
  __syncthreads();

  if (cb == 0) {
    double bsum = 0.0;
    for (int s = tid; s < NS; s += 256) {
      const double x0 = (double)logits[(b * NS + s) * 3 + 0];
      const double x1 = (double)logits[(b * NS + s) * 3 + 1];
      const double x2 = (double)logits[(b * NS + s) * 3 + 2];
      const double m   = fmax(x0, fmax(x1, x2));
      const double lse = log(exp(x0 - m) + exp(x1 - m) + exp(x2 - m));
      const double nll0 = -(x0 - m - lse);
      const double nll1 = -(x1 - m - lse);
      const double nll2 = -(x2 - m - lse);
      dce[((size_t)b * NS + s) * 2 + 0] = nll1 - 0.1 * nll0;
      dce[((size_t)b * NS + s) * 2 + 1] = nll2 - 0.1 * nll0;
      bsum += 0.1 * nll0;
    }
    bsum = wave_sum(bsum);
    if ((tid & 63) == 0) s_bp[tid >> 6] = bsum;
    __syncthreads();
    if (tid == 0) baseCE[b] = (s_bp[0] + s_bp[1]) + (s_bp[2] + s_bp[3]);
  }

  const int nv = s_nv;
  const int i0 = cb * 10;
  const int nrow = (nv - i0 < 10) ? (nv - i0) : 10;
  if (nrow <= 0) return;

  for (int idx = tid; idx < nrow * NP; idx += 256) {
    const int il = idx / NP, k = idx % NP;
    sVT[il * NP + k] = tparams[(b * NG + s_valid[i0 + il]) * NP + k];
  }
  if (tid < nrow) sCls[tid] = s_vlab[i0 + tid];
  __syncthreads();

  for (int e = tid; e < nrow * NS; e += 256) {
    const int il = e / NS, j = e - il * NS;
    const int cls = sCls[il];
    const double p = (double)sP[j * 3 + cls];
    double a[NP];
    #pragma unroll
    for (int k = 0; k < NP; ++k)
      a[k] = fabs((double)sS[j * NP + k] - (double)sVT[il * NP + k]);
    const double coord = ((a[0] + a[1]) + (a[2] + a[3])) +
                         ((a[4] + a[5]) + (a[6] + a[7]));
    const double c = -p + 5.0 * coord + 2.0 * (a[8] + a[9]) +
                     2.0 * (a[0] + a[1]);
    C[((size_t)b * NG + (i0 + il)) * NS + j] = c;
    sC[il * NS + j] = c;
  }
  __syncthreads();

  // fused row minima: wave w reduces rows w, w+4, ...
  const int wid  = tid >> 6;
  const int lane = tid & 63;
  const int vmask = (lane < NS - 4 * 64) ? 0x1F : 0x0F;
  for (int row = wid; row < nrow; row += 4) {
    double bestv = (double)INFINITY;
    int    bestj = 0x7fffffff;
    #pragma unroll
    for (int s = 0; s < NSLOT; ++s) {
      if ((vmask >> s) & 1) {
        const double c = sC[row * NS + lane + 64 * s];
        if (c < bestv) { bestv = c; bestj = lane + 64 * s; }
      }
    }
    double mv; int js;
    wave_argmin(pack_key(bestv), bestj, mv, js);
    if (lane == 0) {
      rowmin[b * NG + i0 + row] = mv;
      rowarg[b * NG + i0 + row] = js;
    }
  }
}

// ---------------------------------------------------------------------------
// Kernel C: JV LAP — warm start + greedy tight claims + SAP with 32-bit DPP
// argmin, speculative row prefetch, LDS row cache; fused loss epilogue;
// last-block finalize (no separate finalize dispatch).
// ---------------------------------------------------------------------------
__global__ __launch_bounds__(64) void detr_match_fast_kernel(
    const float*  __restrict__ strokes,
    const float*  __restrict__ tparams,
    const int*    __restrict__ tlabels,
    const double* __restrict__ C,
    const double* __restrict__ rowmin,
    const int*    __restrict__ rowarg,
    const double* __restrict__ dce,
    const double* __restrict__ baseCE,
    double*       __restrict__ acc,
    unsigned int* __restrict__ cnt,
    float*        __restrict__ out)
{
  __shared__ int    s_valid[NG];
  __shared__ int    s_vlab[NG];
  __shared__ int    s_col4row[NG];
  __shared__ int    s_claimC[NS];
  __shared__ int    s_r4cL[NS];
  __shared__ double s_short[NS];
  __shared__ double s_crow[NCROW * NS];  // 76800 B row cache
  __shared__ int    s_ctag[NCROW];

  const int b    = blockIdx.x;
  const int lane = threadIdx.x;

  for (int j = lane; j < NS; j += 64) {
    s_claimC[j] = 0x7fffffff; s_r4cL[j] = -1;
  }
  if (lane < NCROW) s_ctag[lane] = -1;

  const unsigned long long below = (1ull << lane) - 1ull;
  const int lb1 = tlabels[b * NG + lane];
  const bool in2 = lane < (NG - 64);
  const int lb2 = in2 ? tlabels[b * NG + 64 + lane] : 0;
  const unsigned long long m1 = __ballot(lb1 > 0);
  const unsigned long long m2 = __ballot(in2 && lb2 > 0);
  const int c1 = __popcll(m1);
  if (lb1 > 0) {
    const int p = __popcll(m1 & below);
    s_valid[p] = lane; s_vlab[p] = lb1;
  }
  if (in2 && lb2 > 0) {
    const int p = c1 + __popcll(m2 & below);
    s_valid[p] = 64 + lane; s_vlab[p] = lb2;
  }
  const int nv = c1 + __popcll(m2);

  for (int i = lane; i < nv; i += 64) s_col4row[i] = -1;
  __syncthreads();

  double wnll = 0.0;

  if (nv > 0) {
    const double* Cb = C + (size_t)b * NG * NS;
    const double INF = (double)INFINITY;
    const int vmask = (lane < NS - 4 * 64) ? 0x1F : 0x0F;

    double rm0 = 0.0, rm1 = 0.0;
    int    ra0 = -1,  ra1 = -1;
    if (lane < nv) {
      rm0 = rowmin[b * NG + lane];
      ra0 = rowarg[b * NG + lane];
    }
    if (lane + 64 < nv) {
      rm1 = rowmin[b * NG + lane + 64];
      ra1 = rowarg[b * NG + lane + 64];
    }

    if (lane < nv)      atomicMin(&s_claimC[ra0], lane);
    if (lane + 64 < nv) atomicMin(&s_claimC[ra1], lane + 64);
    __syncthreads();
    if (lane < nv && s_claimC[ra0] == lane) {
      s_r4cL[ra0] = lane; s_col4row[lane] = ra0;
    }
    if (lane + 64 < nv && s_claimC[ra1] == lane + 64) {
      s_r4cL[ra1] = lane + 64; s_col4row[lane + 64] = ra1;
    }
    __syncthreads();

    int r4c[NSLOT];
    #pragma unroll
    for (int s = 0; s < NSLOT; ++s)
      r4c[s] = ((vmask >> s) & 1) ? s_r4cL[lane + 64 * s] : -1;
    double vv[NSLOT];
    #pragma unroll
    for (int s = 0; s < NSLOT; ++s) vv[s] = 0.0;

    double u0 = rm0, u1 = rm1;

    unsigned long long f0 = __ballot(lane < nv && s_col4row[lane] < 0);
    unsigned long long f1 = __ballot(lane + 64 < nv && s_col4row[lane + 64] < 0);

    int pf_row = -1;
    double pfv[NSLOT];
    #pragma unroll
    for (int s = 0; s < NSLOT; ++s) pfv[s] = 0.0;

#define PRELOAD(ROW) do { \
      const double* Pr_ = Cb + (size_t)(ROW) * NS; \
      pfv[0] = Pr_[lane]; \
      pfv[1] = Pr_[lane + 64]; \
      pfv[2] = Pr_[lane + 128]; \
      pfv[3] = Pr_[lane + 192]; \
      if (lane < NS - 256) pfv[4] = Pr_[lane + 256]; \
    } while (0)

    {
      int n = -1;
      if (f0) n = __ffsll(f0) - 1; else if (f1) n = 64 + __ffsll(f1) - 1;
      if (n >= 0) { pf_row = n; PRELOAD(n); }
    }

    while (f0 | f1) {
      int cur;
      if (f0) { cur = __ffsll(f0) - 1; f0 &= f0 - 1; }
      else    { cur = 64 + __ffsll(f1) - 1; f1 &= f1 - 1; }

      double sh[NSLOT];
      int    pa[NSLOT];
      #pragma unroll
      for (int s = 0; s < NSLOT; ++s) { sh[s] = INF; pa[s] = -1; }
      int scm = 0;
      unsigned long long srm0 = 0ull, srm1 = 0ull;
      double minVal = 0.0;
      int i = cur;
      int sink = -1;

      while (sink == -1) {
        if (i < 64) srm0 |= (1ull << i); else srm1 |= (1ull << (i - 64));
        const double ucur = (i < 64) ? rl_f64(u0, i) : rl_f64(u1, i - 64);
        const double base = minVal - ucur;

        // row values: prefetch regs > LDS cache > global (+fill cache)
        const int cs = i & (NCROW - 1);
        const bool cached = (s_ctag[cs] == i);
        double cv[NSLOT];
        if (i == pf_row) {
          #pragma unroll
          for (int s = 0; s < NSLOT; ++s) cv[s] = pfv[s];
          if (!cached) {
            #pragma unroll
            for (int s = 0; s < NSLOT; ++s)
              if ((vmask >> s) & 1) s_crow[cs * NS + lane + 64 * s] = pfv[s];
            if (lane == 0) s_ctag[cs] = i;
          }
        } else if (cached) {
          #pragma unroll
          for (int s = 0; s < NSLOT; ++s)
            if ((vmask >> s) & 1) cv[s] = s_crow[cs * NS + lane + 64 * s];
        } else {
          const double* Gr = Cb + (size_t)i * NS;
          #pragma unroll
          for (int s = 0; s < NSLOT; ++s)
            if ((vmask >> s) & 1) cv[s] = Gr[lane + 64 * s];
          #pragma unroll
          for (int s = 0; s < NSLOT; ++s)
            if ((vmask >> s) & 1) s_crow[cs * NS + lane + 64 * s] = cv[s];
          if (lane == 0) s_ctag[cs] = i;
        }

        double bestv = INF;
        int    bestj = 0x7fffffff;
        #pragma unroll
        for (int s = 0; s < NSLOT; ++s) {
          if ((vmask >> s) & 1) {
            if (!((scm >> s) & 1)) {
              const double dd = base + cv[s] - vv[s];
              if (dd < sh[s]) { sh[s] = dd; pa[s] = i; }
              if (sh[s] < bestv) { bestv = sh[s]; bestj = lane + 64 * s; }
            }
          }
        }

        const int src = argmin32_src(bestv);
        const int jstar = __builtin_amdgcn_readlane(bestj, src);
        minVal = rl_f64(bestv, src);
        const int slot = jstar >> 6;
        const int jl   = jstar & 63;
        if (lane == jl) scm |= (1 << slot);

        int t;
        GET_SLOT(r4c, slot, t);
        const int rc = __builtin_amdgcn_readlane(t, jl);
        if (rc < 0) {
          sink = jstar;
        } else {
          i = rc;
          double b2 = INF;
          int    bj2 = 0x7fffffff;
          #pragma unroll
          for (int s = 0; s < NSLOT; ++s) {
            if ((vmask >> s) & 1) {
              if (!((scm >> s) & 1) && sh[s] < b2) {
                b2 = sh[s]; bj2 = lane + 64 * s;
              }
            }
          }
          const int src2 = argmin32_src(b2);
          const int j2 = __builtin_amdgcn_readlane(bj2, src2);
          int t2;
          GET_SLOT(r4c, (j2 >> 6), t2);
          const int rc2 = __builtin_amdgcn_readlane(t2, j2 & 63);
          if (rc2 >= 0 && rc2 != i && s_ctag[rc2 & (NCROW - 1)] != rc2) {
            pf_row = rc2; PRELOAD(rc2);
          } else pf_row = -1;
        }
      }

      #pragma unroll
      for (int s = 0; s < NSLOT; ++s)
        if ((vmask >> s) & 1) s_short[lane + 64 * s] = sh[s];
      __syncthreads();

      if (((srm0 >> lane) & 1ull) && lane != cur)
        u0 += minVal - s_short[s_col4row[lane]];
      const int r2 = lane + 64;
      if (((srm1 >> lane) & 1ull) && r2 != cur)
        u1 += minVal - s_short[s_col4row[r2]];
      if (lane == cur) u0 += minVal;
      if (r2 == cur)   u1 += minVal;
      #pragma unroll
      for (int s = 0; s < NSLOT; ++s)
        if ((scm >> s) & 1) vv[s] -= minVal - sh[s];
      __syncthreads();

      // augmenting-path flip
      int j = sink;
      while (true) {
        const int slot = j >> 6, src3 = j & 63;
        int t;
        GET_SLOT(pa, slot, t);
        const int i2 = __builtin_amdgcn_readlane(t, src3);
        if (lane == src3) SET_SLOT(r4c, slot, i2);
        const int nxt = s_col4row[i2];
        if (lane == 0) s_col4row[i2] = j;
        if (i2 == cur) break;
        j = nxt;
      }
      __syncthreads();

      {
        int n = -1;
        if (f0) n = __ffsll(f0) - 1; else if (f1) n = 64 + __ffsll(f1) - 1;
        if (n >= 0) { pf_row = n; PRELOAD(n); }
      }
    }
#undef PRELOAD

    // matched regression partials + CE delta gathers
    double l1 = 0.0, sl1 = 0.0, wid = 0.0;
    for (int i = lane; i < nv; i += 64) {
      const int r = s_col4row[i];
      const int c = s_vlab[i];
      wnll += dce[((size_t)b * NS + r) * 2 + (c - 1)];
      const float* ps = strokes + ((size_t)b * NS + r) * NP;
      const float* tp = tparams + ((size_t)b * NG + s_valid[i]) * NP;
      #pragma unroll
      for (int k = 0; k < 8; ++k) {
        const float d  = ps[k] - tp[k];
        const float ad = fabsf(d);
        l1 += (double)ad;
        const float sm = (ad < 0.1f) ? (0.5f * ad * ad / 0.1f) : (ad - 0.05f);
        sl1 += (double)sm;
      }
      const float d8 = fabsf(ps[8] - tp[8]);
      const float d9 = fabsf(ps[9] - tp[9]);
      wid += (double)d8 + (double)d9;
    }
    l1 = wave_sum(l1); sl1 = wave_sum(sl1); wid = wave_sum(wid);
    if (lane == 0) {
      atomicAdd(&acc[2], l1);
      atomicAdd(&acc[3], sl1);
      atomicAdd(&acc[4], wid);
      atomicAdd(&acc[5], (double)nv);
    }
  }

  wnll = wave_sum(wnll);
  if (lane == 0) {
    atomicAdd(&acc[0], wnll + baseCE[b]);
    atomicAdd(&acc[1], 30.0 + 0.9 * (double)nv);

    // last-block finalize (device-scope counter; coherent acc readback)
    __threadfence();
    const unsigned int done = atomicAdd(cnt, 1u);
    if (done == NB - 1) {
      __threadfence();
      const double a0 = atomicAdd(&acc[0], 0.0);
      const double a1 = atomicAdd(&acc[1], 0.0);
      const double a2 = atomicAdd(&acc[2], 0.0);
      const double a3 = atomicAdd(&acc[3], 0.0);
      const double a4 = atomicAdd(&acc[4], 0.0);
      const double a5 = atomicAdd(&acc[5], 0.0);
      const double denom = fmax(a5, 1.0);
      out[0] = (float)(a0 / a1 + 5.0 * (a2 + a3) / denom + 2.0 * a4 / denom);
    }
  }
}

// ---------------------------------------------------------------------------
// Fallback (ws too small): round-0 monolithic kernel (proven, absmax 0.0).
// ---------------------------------------------------------------------------
__global__ __launch_bounds__(64) void detr_match_loss_kernel(
    const float* __restrict__ strokes,
    const float* __restrict__ logits,
    const float* __restrict__ tparams,
    const int*   __restrict__ tlabels,
    double*      __restrict__ acc)
{
  __shared__ float  s_strokes[NS * NP];
  __shared__ float  s_probs[NS * 3];
  __shared__ float  s_vt[NG * NP];
  __shared__ int    s_valid[NG];
  __shared__ int    s_vlab[NG];
  __shared__ double s_u[NG];
  __shared__ int    s_col4row[NG];
  __shared__ int    s_SRb[NG];
  __shared__ double s_shortest[NS];
  __shared__ double s_v[NS];
  __shared__ int    s_path[NS];
  __shared__ int    s_SC[NS];
  __shared__ int    s_row4col[NS];
  __shared__ int    s_tc[NS];
  __shared__ int    s_nv;

  const int b    = blockIdx.x;
  const int lane = threadIdx.x;

  for (int idx = lane; idx < NS * NP; idx += 64)
    s_strokes[idx] = strokes[b * NS * NP + idx];

  for (int j = lane; j < NS; j += 64) {
    const float x0 = logits[(b * NS + j) * 3 + 0];
    const float x1 = logits[(b * NS + j) * 3 + 1];
    const float x2 = logits[(b * NS + j) * 3 + 2];
    const float m  = fmaxf(x0, fmaxf(x1, x2));
    const float e0 = expf(x0 - m), e1 = expf(x1 - m), e2 = expf(x2 - m);
    const float s  = e0 + e1 + e2;
    s_probs[j * 3 + 0] = e0 / s;
    s_probs[j * 3 + 1] = e1 / s;
    s_probs[j * 3 + 2] = e2 / s;
    s_tc[j]      = 0;
    s_row4col[j] = -1;
    s_v[j]       = 0.0;
  }

  if (lane == 0) {
    int nv = 0;
    for (int g = 0; g < NG; ++g) {
      const int lb = tlabels[b * NG + g];
      if (lb > 0) { s_valid[nv] = g; s_vlab[nv] = lb; ++nv; }
    }
    s_nv = nv;
  }
  __syncthreads();
  const int nv = s_nv;

  for (int idx = lane; idx < nv * NP; idx += 64) {
    const int i = idx / NP, k = idx % NP;
    s_vt[idx] = tparams[(b * NG + s_valid[i]) * NP + k];
  }
  for (int i = lane; i < nv; i += 64) { s_u[i] = 0.0; s_col4row[i] = -1; }
  __syncthreads();

  if (nv > 0) {
    for (int cur = 0; cur < nv; ++cur) {
      for (int j = lane; j < NS; j += 64) {
        s_shortest[j] = 1e300;
        s_path[j]     = -1;
        s_SC[j]       = 0;
      }
      for (int r = lane; r < nv; r += 64) s_SRb[r] = 0;
      __syncthreads();

      double minVal = 0.0;
      int i = cur;
      int sink = -1;

      while (sink == -1) {
        if (lane == 0) s_SRb[i] = 1;
        const double ui  = s_u[i];
        const int    cls = s_vlab[i];
        double vtr[NP];
        #pragma unroll
        for (int k = 0; k < NP; ++k) vtr[k] = (double)s_vt[i * NP + k];
        const double base = minVal - ui;

        double bestv = 1e300;
        int    bestj = 0x7fffffff;

        for (int j = lane; j < NS; j += 64) {
          if (!s_SC[j]) {
            const double p = (double)s_probs[j * 3 + cls];
            double a[NP];
            #pragma unroll
            for (int k = 0; k < NP; ++k)
              a[k] = fabs((double)s_strokes[j * NP + k] - vtr[k]);
            const double coord = ((a[0] + a[1]) + (a[2] + a[3])) +
                                 ((a[4] + a[5]) + (a[6] + a[7]));
            const double c = -p + 5.0 * coord + 2.0 * (a[8] + a[9]) +
                             2.0 * (a[0] + a[1]);
            const double d = base + c - s_v[j];
            if (d < s_shortest[j]) { s_shortest[j] = d; s_path[j] = i; }
            const double sv = s_shortest[j];
            if (sv < bestv) { bestv = sv; bestj = j; }
          }
        }

        #pragma unroll
        for (int off = 32; off > 0; off >>= 1) {
          const double ov = __shfl_xor(bestv, off);
          const int    oj = __shfl_xor(bestj, off);
          if (ov < bestv || (ov == bestv && oj < bestj)) { bestv = ov; bestj = oj; }
        }
        minVal = bestv;
        const int jstar = bestj;
        if (lane == 0) s_SC[jstar] = 1;
        __syncthreads();
        const int rc = s_row4col[jstar];
        if (rc < 0) sink = jstar; else i = rc;
      }

      for (int r = lane; r < nv; r += 64)
        if (s_SRb[r] && r != cur)
          s_u[r] += minVal - s_shortest[s_col4row[r]];
      if (lane == 0) s_u[cur] += minVal;
      for (int j = lane; j < NS; j += 64)
        if (s_SC[j]) s_v[j] -= minVal - s_shortest[j];
      __syncthreads();

      if (lane == 0) {
        int j = sink;
        while (true) {
          const int i2 = s_path[j];
          s_row4col[j] = i2;
          const int nxt = s_col4row[i2];
          s_col4row[i2] = j;
          if (i2 == cur) break;
          j = nxt;
        }
      }
      __syncthreads();
    }

    double l1 = 0.0, sl1 = 0.0, wid = 0.0;
    for (int i = lane; i < nv; i += 64) {
      const int r = s_col4row[i];
      s_tc[r] = s_vlab[i];
      #pragma unroll
      for (int k = 0; k < 8; ++k) {
        const float d  = s_strokes[r * NP + k] - s_vt[i * NP + k];
        const float ad = fabsf(d);
        l1 += (double)ad;
        const float s = (ad < 0.1f) ? (0.5f * ad * ad / 0.1f) : (ad - 0.05f);
        sl1 += (double)s;
      }
      const float d8 = fabsf(s_strokes[r * NP + 8] - s_vt[i * NP + 8]);
      const float d9 = fabsf(s_strokes[r * NP + 9] - s_vt[i * NP + 9]);
      wid += (double)d8 + (double)d9;
    }
    l1 = wave_sum(l1); sl1 = wave_sum(sl1); wid = wave_sum(wid);
    if (lane == 0) {
      atomicAdd(&acc[2], l1);
      atomicAdd(&acc[3], sl1);
      atomicAdd(&acc[4], wid);
      atomicAdd(&acc[5], (double)nv);
    }
  }
  __syncthreads();

  double wnll = 0.0, wsum = 0.0;
  for (int s = lane; s < NS; s += 64) {
    const int tc = s_tc[s];
    const double x0 = (double)logits[(b * NS + s) * 3 + 0];
    const double x1 = (double)logits[(b * NS + s) * 3 + 1];
    const double x2 = (double)logits[(b * NS + s) * 3 + 2];
    const double m   = fmax(x0, fmax(x1, x2));
    const double lse = log(exp(x0 - m) + exp(x1 - m) + exp(x2 - m));
    const double xt  = (tc == 0) ? x0 : ((tc == 1) ? x1 : x2);
    const double nll = -(xt - m - lse);
    const double w   = (tc == 0) ? 0.1 : 1.0;
    wnll += w * nll;
    wsum += w;
  }
  wnll = wave_sum(wnll); wsum = wave_sum(wsum);
  if (lane == 0) {
    atomicAdd(&acc[0], wnll);
    atomicAdd(&acc[1], wsum);
  }
}

__global__ void detr_finalize_kernel(const double* __restrict__ acc,
                                     float* __restrict__ out) {
  const double loss_ce = acc[0] / acc[1];
  const double denom   = fmax(acc[5], 1.0);
  const double loss = 1.0 * loss_ce
                    + 5.0 * (acc[2] + acc[3]) / denom
                    + 2.0 * acc[4] / denom;
  out[0] = (float)loss;
}

extern "C" void kernel_launch(void* const* d_in, const int* in_sizes, int n_in,
                              void* d_out, int out_size, void* d_ws, size_t ws_size,
                              hipStream_t stream) {
  const float* strokes = (const float*)d_in[0];
  const float* logits  = (const float*)d_in[1];
  const float* tparams = (const float*)d_in[2];
  const int*   tlabels = (const int*)d_in[3];
  char* ws = (char*)d_ws;
  double* acc = (double*)(ws + WS_ACC);

  if (ws_size >= WS_NEEDED) {
    double* rowmin = (double*)(ws + WS_ROWMIN);
    int*    rowarg = (int*)(ws + WS_ROWARG);
    double* dce    = (double*)(ws + WS_DCE);
    double* baseCE = (double*)(ws + WS_BASECE);
    double* C      = (double*)(ws + WS_C);
    unsigned int* cnt = (unsigned int*)(ws + 48);

    detr_cost_kernel<<<dim3(NB, 10), 256, 0, stream>>>(
        strokes, logits, tparams, tlabels, C, dce, baseCE, rowmin, rowarg, acc);
    detr_match_fast_kernel<<<NB, 64, 0, stream>>>(
        strokes, tparams, tlabels, C, rowmin, rowarg, dce, baseCE, acc, cnt,
        (float*)d_out);
  } else {
    hipMemsetAsync(d_ws, 0, 64, stream);
    detr_match_loss_kernel<<<NB, 64, 0, stream>>>(strokes, logits, tparams,
                                                  tlabels, acc);
    detr_finalize_kernel<<<1, 1, 0, stream>>>(acc, (float*)d_out);
  }
}

// Round 11
// 67.037 us; speedup vs baseline: 1.1615x; 1.0720x over previous
//
#include <hip/hip_runtime.h>
#include <math.h>
#include <stdint.h>

#define NB 128
#define NS 300   // pred slots (columns)
#define NG 100   // gt slots (max rows)
#define NP 10    // params per stroke
#define NSLOT 5  // ceil(NS/64)

// ws layout (all 8-aligned):
#define WS_ACC     0                         // 6 doubles + counter @48 (64 B)
#define WS_ROWMIN  1024                      // NB*NG*8 = 102400
#define WS_ROWARG  103424                    // NB*NG*4 = 51200
#define WS_DCE     154624                    // NB*NS*2*8 = 614400
#define WS_BASECE  769024                    // NB*8 (pad to 1024)
#define WS_C       770048                    // NB*NG*NS*8 = 30720000
#define WS_NEEDED  (WS_C + (size_t)NB * NG * NS * 8)

#define GET_SLOT(arr, slot, out) do { switch (slot) { \
  case 0: out = arr[0]; break; case 1: out = arr[1]; break; \
  case 2: out = arr[2]; break; case 3: out = arr[3]; break; \
  default: out = arr[4]; break; } } while (0)
#define SET_SLOT(arr, slot, val) do { switch (slot) { \
  case 0: arr[0] = val; break; case 1: arr[1] = val; break; \
  case 2: arr[2] = val; break; case 3: arr[3] = val; break; \
  default: arr[4] = val; break; } } while (0)

__device__ __forceinline__ double wave_sum(double v) {
  #pragma unroll
  for (int off = 32; off > 0; off >>= 1) v += __shfl_xor(v, off);
  return v;
}

// ---- order-preserving f64 <-> u64 key ----
__device__ __forceinline__ uint64_t pack_key(double d) {
  const uint64_t b = (uint64_t)__double_as_longlong(d);
  return (b >> 63) ? ~b : (b | 0x8000000000000000ull);
}
__device__ __forceinline__ double unpack_key(uint64_t k) {
  const uint64_t b = (k >> 63) ? (k & 0x7fffffffffffffffull) : ~k;
  return __longlong_as_double((long long)b);
}

__device__ __forceinline__ double rl_f64(double v, int src) {
  const uint64_t b = (uint64_t)__double_as_longlong(v);
  const int lo = __builtin_amdgcn_readlane((int)(uint32_t)b, src);
  const int hi = __builtin_amdgcn_readlane((int)(uint32_t)(b >> 32), src);
  return __longlong_as_double((long long)(((uint64_t)(uint32_t)hi << 32) |
                                          (uint32_t)lo));
}

template <int CTRL>
__device__ __forceinline__ uint64_t dpp_u64_or_max(uint64_t x) {
  const int lo = (int)(uint32_t)x;
  const int hi = (int)(uint32_t)(x >> 32);
  const int lo2 = __builtin_amdgcn_update_dpp(-1, lo, CTRL, 0xF, 0xF, false);
  const int hi2 = __builtin_amdgcn_update_dpp(-1, hi, CTRL, 0xF, 0xF, false);
  return ((uint64_t)(uint32_t)hi2 << 32) | (uint32_t)lo2;
}

__device__ __forceinline__ void wave_argmin(uint64_t key, int bestj,
                                            double& minVal, int& jstar) {
  uint64_t k = key;
  { const uint64_t o = dpp_u64_or_max<0x111>(k); if (o < k) k = o; }
  { const uint64_t o = dpp_u64_or_max<0x112>(k); if (o < k) k = o; }
  { const uint64_t o = dpp_u64_or_max<0x114>(k); if (o < k) k = o; }
  { const uint64_t o = dpp_u64_or_max<0x118>(k); if (o < k) k = o; }
  { const uint64_t o = dpp_u64_or_max<0x142>(k); if (o < k) k = o; }
  { const uint64_t o = dpp_u64_or_max<0x143>(k); if (o < k) k = o; }
  const uint32_t mlo = (uint32_t)__builtin_amdgcn_readlane((int)(uint32_t)k, 63);
  const uint32_t mhi = (uint32_t)__builtin_amdgcn_readlane((int)(uint32_t)(k >> 32), 63);
  const uint64_t minkey = ((uint64_t)mhi << 32) | mlo;
  const unsigned long long winners = __ballot(key == minkey);
  const int src = __ffsll(winners) - 1;
  jstar = __builtin_amdgcn_readlane(bestj, src);
  minVal = unpack_key(minkey);
}

// ---- fast 32-bit-high-word DPP argmin with exact tie resolution ----
__device__ __forceinline__ int argmin32_src(double bestv) {
  const uint64_t key = pack_key(bestv);
  const uint32_t hi = (uint32_t)(key >> 32);
  int x = (int)hi;
  { const int o = __builtin_amdgcn_update_dpp(-1, x, 0x111, 0xF, 0xF, false);
    x = ((uint32_t)o < (uint32_t)x) ? o : x; }
  { const int o = __builtin_amdgcn_update_dpp(-1, x, 0x112, 0xF, 0xF, false);
    x = ((uint32_t)o < (uint32_t)x) ? o : x; }
  { const int o = __builtin_amdgcn_update_dpp(-1, x, 0x114, 0xF, 0xF, false);
    x = ((uint32_t)o < (uint32_t)x) ? o : x; }
  { const int o = __builtin_amdgcn_update_dpp(-1, x, 0x118, 0xF, 0xF, false);
    x = ((uint32_t)o < (uint32_t)x) ? o : x; }
  { const int o = __builtin_amdgcn_update_dpp(-1, x, 0x142, 0xF, 0xF, false);
    x = ((uint32_t)o < (uint32_t)x) ? o : x; }
  { const int o = __builtin_amdgcn_update_dpp(-1, x, 0x143, 0xF, 0xF, false);
    x = ((uint32_t)o < (uint32_t)x) ? o : x; }
  const uint32_t minhi = (uint32_t)__builtin_amdgcn_readlane(x, 63);
  unsigned long long cand = __ballot(hi == minhi);
  int src = __ffsll(cand) - 1;
  if (__popcll(cand) > 1) {
    uint64_t bk = ~0ull; int bs = src;
    while (cand) {
      const int l = __ffsll(cand) - 1; cand &= cand - 1;
      const uint32_t klo = (uint32_t)__builtin_amdgcn_readlane((int)(uint32_t)key, l);
      const uint32_t khi = (uint32_t)__builtin_amdgcn_readlane((int)(uint32_t)(key >> 32), l);
      const uint64_t kk = ((uint64_t)khi << 32) | klo;
      if (kk < bk) { bk = kk; bs = l; }
    }
    src = bs;
  }
  return src;
}

// ---------------------------------------------------------------------------
// Kernel B: cost matrix C (f64, bitwise == numpy) + fused row minima + CE
// decomposition (cb==0) + acc/counter zero-init (block 0,0).
// ---------------------------------------------------------------------------
__global__ __launch_bounds__(256) void detr_cost_kernel(
    const float* __restrict__ strokes,
    const float* __restrict__ logits,
    const float* __restrict__ tparams,
    const int*   __restrict__ tlabels,
    double*      __restrict__ C,
    double*      __restrict__ dce,
    double*      __restrict__ baseCE,
    double*      __restrict__ rowmin,
    int*         __restrict__ rowarg,
    double*      __restrict__ acc)
{
  __shared__ float  sS[NS * NP];
  __shared__ float  sP[NS * 3];
  __shared__ float  sVT[10 * NP];
  __shared__ int    sCls[10];
  __shared__ int    s_valid[NG];
  __shared__ int    s_vlab[NG];
  __shared__ int    s_nv;
  __shared__ double s_bp[4];
  __shared__ double sC[10 * NS];

  const int b   = blockIdx.x;
  const int cb  = blockIdx.y;
  const int tid = threadIdx.x;

  if (b == 0 && cb == 0 && tid < 8)
    acc[tid] = 0.0;   // zeroes 6 accumulators + the completion counter @48

  for (int idx = tid; idx < NS * NP; idx += 256)
    sS[idx] = strokes[b * NS * NP + idx];

  for (int j = tid; j < NS; j += 256) {
    const float x0 = logits[(b * NS + j) * 3 + 0];
    const float x1 = logits[(b * NS + j) * 3 + 1];
    const float x2 = logits[(b * NS + j) * 3 + 2];
    const float m  = fmaxf(x0, fmaxf(x1, x2));
    const float e0 = expf(x0 - m), e1 = expf(x1 - m), e2 = expf(x2 - m);
    const float s  = e0 + e1 + e2;
    sP[j * 3 + 0] = e0 / s;
    sP[j * 3 + 1] = e1 / s;
    sP[j * 3 + 2] = e2 / s;
  }

  if (tid < 64) {
    const unsigned long long below = (1ull << tid) - 1ull;
    const int lb1 = tlabels[b * NG + tid];
    const bool in2 = tid < (NG - 64);
    const int lb2 = in2 ? tlabels[b * NG + 64 + tid] : 0;
    const unsigned long long m1 = __ballot(lb1 > 0);
    const unsigned long long m2 = __ballot(in2 && lb2 > 0);
    const int c1 = __popcll(m1);
    if (lb1 > 0) {
      const int p = __popcll(m1 & below);
      s_valid[p] = tid; s_vlab[p] = lb1;
    }
    if (in2 && lb2 > 0) {
      const int p = c1 + __popcll(m2 & below);
      s_valid[p] = 64 + tid; s_vlab[p] = lb2;
    }
    if (tid == 0) s_nv = c1 + __popcll(m2);
  }
  __syncthreads();

  if (cb == 0) {
    double bsum = 0.0;
    for (int s = tid; s < NS; s += 256) {
      const double x0 = (double)logits[(b * NS + s) * 3 + 0];
      const double x1 = (double)logits[(b * NS + s) * 3 + 1];
      const double x2 = (double)logits[(b * NS + s) * 3 + 2];
      const double m   = fmax(x0, fmax(x1, x2));
      const double lse = log(exp(x0 - m) + exp(x1 - m) + exp(x2 - m));
      const double nll0 = -(x0 - m - lse);
      const double nll1 = -(x1 - m - lse);
      const double nll2 = -(x2 - m - lse);
      dce[((size_t)b * NS + s) * 2 + 0] = nll1 - 0.1 * nll0;
      dce[((size_t)b * NS + s) * 2 + 1] = nll2 - 0.1 * nll0;
      bsum += 0.1 * nll0;
    }
    bsum = wave_sum(bsum);
    if ((tid & 63) == 0) s_bp[tid >> 6] = bsum;
    __syncthreads();
    if (tid == 0) baseCE[b] = (s_bp[0] + s_bp[1]) + (s_bp[2] + s_bp[3]);
  }

  const int nv = s_nv;
  const int i0 = cb * 10;
  const int nrow = (nv - i0 < 10) ? (nv - i0) : 10;
  if (nrow <= 0) return;

  for (int idx = tid; idx < nrow * NP; idx += 256) {
    const int il = idx / NP, k = idx % NP;
    sVT[il * NP + k] = tparams[(b * NG + s_valid[i0 + il]) * NP + k];
  }
  if (tid < nrow) sCls[tid] = s_vlab[i0 + tid];
  __syncthreads();

  for (int e = tid; e < nrow * NS; e += 256) {
    const int il = e / NS, j = e - il * NS;
    const int cls = sCls[il];
    const double p = (double)sP[j * 3 + cls];
    double a[NP];
    #pragma unroll
    for (int k = 0; k < NP; ++k)
      a[k] = fabs((double)sS[j * NP + k] - (double)sVT[il * NP + k]);
    const double coord = ((a[0] + a[1]) + (a[2] + a[3])) +
                         ((a[4] + a[5]) + (a[6] + a[7]));
    const double c = -p + 5.0 * coord + 2.0 * (a[8] + a[9]) +
                     2.0 * (a[0] + a[1]);
    C[((size_t)b * NG + (i0 + il)) * NS + j] = c;
    sC[il * NS + j] = c;
  }
  __syncthreads();

  // fused row minima: wave w reduces rows w, w+4, ...
  const int wid  = tid >> 6;
  const int lane = tid & 63;
  const int vmask = (lane < NS - 4 * 64) ? 0x1F : 0x0F;
  for (int row = wid; row < nrow; row += 4) {
    double bestv = (double)INFINITY;
    int    bestj = 0x7fffffff;
    #pragma unroll
    for (int s = 0; s < NSLOT; ++s) {
      if ((vmask >> s) & 1) {
        const double c = sC[row * NS + lane + 64 * s];
        if (c < bestv) { bestv = c; bestj = lane + 64 * s; }
      }
    }
    double mv; int js;
    wave_argmin(pack_key(bestv), bestj, mv, js);
    if (lane == 0) {
      rowmin[b * NG + i0 + row] = mv;
      rowarg[b * NG + i0 + row] = js;
    }
  }
}

// ---------------------------------------------------------------------------
// Kernel C: JV LAP — warm start + greedy tight claims + SAP with 32-bit DPP
// argmin + speculative row prefetch (NO LDS row cache — r10 showed the tag
// check in the serial chain costs more than the hits save); fused loss
// epilogue; last-block finalize.
// ---------------------------------------------------------------------------
__global__ __launch_bounds__(64) void detr_match_fast_kernel(
    const float*  __restrict__ strokes,
    const float*  __restrict__ tparams,
    const int*    __restrict__ tlabels,
    const double* __restrict__ C,
    const double* __restrict__ rowmin,
    const int*    __restrict__ rowarg,
    const double* __restrict__ dce,
    const double* __restrict__ baseCE,
    double*       __restrict__ acc,
    unsigned int* __restrict__ cnt,
    float*        __restrict__ out)
{
  __shared__ int    s_valid[NG];
  __shared__ int    s_vlab[NG];
  __shared__ int    s_col4row[NG];
  __shared__ int    s_claimC[NS];
  __shared__ int    s_r4cL[NS];
  __shared__ double s_short[NS];

  const int b    = blockIdx.x;
  const int lane = threadIdx.x;

  for (int j = lane; j < NS; j += 64) {
    s_claimC[j] = 0x7fffffff; s_r4cL[j] = -1;
  }

  const unsigned long long below = (1ull << lane) - 1ull;
  const int lb1 = tlabels[b * NG + lane];
  const bool in2 = lane < (NG - 64);
  const int lb2 = in2 ? tlabels[b * NG + 64 + lane] : 0;
  const unsigned long long m1 = __ballot(lb1 > 0);
  const unsigned long long m2 = __ballot(in2 && lb2 > 0);
  const int c1 = __popcll(m1);
  if (lb1 > 0) {
    const int p = __popcll(m1 & below);
    s_valid[p] = lane; s_vlab[p] = lb1;
  }
  if (in2 && lb2 > 0) {
    const int p = c1 + __popcll(m2 & below);
    s_valid[p] = 64 + lane; s_vlab[p] = lb2;
  }
  const int nv = c1 + __popcll(m2);

  for (int i = lane; i < nv; i += 64) s_col4row[i] = -1;
  __syncthreads();

  double wnll = 0.0;

  if (nv > 0) {
    const double* Cb = C + (size_t)b * NG * NS;
    const double INF = (double)INFINITY;
    const int vmask = (lane < NS - 4 * 64) ? 0x1F : 0x0F;

    double rm0 = 0.0, rm1 = 0.0;
    int    ra0 = -1,  ra1 = -1;
    if (lane < nv) {
      rm0 = rowmin[b * NG + lane];
      ra0 = rowarg[b * NG + lane];
    }
    if (lane + 64 < nv) {
      rm1 = rowmin[b * NG + lane + 64];
      ra1 = rowarg[b * NG + lane + 64];
    }

    if (lane < nv)      atomicMin(&s_claimC[ra0], lane);
    if (lane + 64 < nv) atomicMin(&s_claimC[ra1], lane + 64);
    __syncthreads();
    if (lane < nv && s_claimC[ra0] == lane) {
      s_r4cL[ra0] = lane; s_col4row[lane] = ra0;
    }
    if (lane + 64 < nv && s_claimC[ra1] == lane + 64) {
      s_r4cL[ra1] = lane + 64; s_col4row[lane + 64] = ra1;
    }
    __syncthreads();

    int r4c[NSLOT];
    #pragma unroll
    for (int s = 0; s < NSLOT; ++s)
      r4c[s] = ((vmask >> s) & 1) ? s_r4cL[lane + 64 * s] : -1;
    double vv[NSLOT];
    #pragma unroll
    for (int s = 0; s < NSLOT; ++s) vv[s] = 0.0;

    double u0 = rm0, u1 = rm1;

    unsigned long long f0 = __ballot(lane < nv && s_col4row[lane] < 0);
    unsigned long long f1 = __ballot(lane + 64 < nv && s_col4row[lane + 64] < 0);

    int pf_row = -1;
    double pfv[NSLOT];
    #pragma unroll
    for (int s = 0; s < NSLOT; ++s) pfv[s] = 0.0;

#define PRELOAD(ROW) do { \
      const double* Pr_ = Cb + (size_t)(ROW) * NS; \
      pfv[0] = Pr_[lane]; \
      pfv[1] = Pr_[lane + 64]; \
      pfv[2] = Pr_[lane + 128]; \
      pfv[3] = Pr_[lane + 192]; \
      if (lane < NS - 256) pfv[4] = Pr_[lane + 256]; \
    } while (0)

    {
      int n = -1;
      if (f0) n = __ffsll(f0) - 1; else if (f1) n = 64 + __ffsll(f1) - 1;
      if (n >= 0) { pf_row = n; PRELOAD(n); }
    }

    while (f0 | f1) {
      int cur;
      if (f0) { cur = __ffsll(f0) - 1; f0 &= f0 - 1; }
      else    { cur = 64 + __ffsll(f1) - 1; f1 &= f1 - 1; }

      double sh[NSLOT];
      int    pa[NSLOT];
      #pragma unroll
      for (int s = 0; s < NSLOT; ++s) { sh[s] = INF; pa[s] = -1; }
      int scm = 0;
      unsigned long long srm0 = 0ull, srm1 = 0ull;
      double minVal = 0.0;
      int i = cur;
      int sink = -1;

      while (sink == -1) {
        if (i < 64) srm0 |= (1ull << i); else srm1 |= (1ull << (i - 64));
        const double ucur = (i < 64) ? rl_f64(u0, i) : rl_f64(u1, i - 64);
        const double base = minVal - ucur;

        double cv[NSLOT];
        if (i == pf_row) {
          #pragma unroll
          for (int s = 0; s < NSLOT; ++s) cv[s] = pfv[s];
        } else {
          const double* Gr = Cb + (size_t)i * NS;
          #pragma unroll
          for (int s = 0; s < NSLOT; ++s)
            if ((vmask >> s) & 1) cv[s] = Gr[lane + 64 * s];
        }

        double bestv = INF;
        int    bestj = 0x7fffffff;
        #pragma unroll
        for (int s = 0; s < NSLOT; ++s) {
          if ((vmask >> s) & 1) {
            if (!((scm >> s) & 1)) {
              const double dd = base + cv[s] - vv[s];
              if (dd < sh[s]) { sh[s] = dd; pa[s] = i; }
              if (sh[s] < bestv) { bestv = sh[s]; bestj = lane + 64 * s; }
            }
          }
        }

        const int src = argmin32_src(bestv);
        const int jstar = __builtin_amdgcn_readlane(bestj, src);
        minVal = rl_f64(bestv, src);
        const int slot = jstar >> 6;
        const int jl   = jstar & 63;
        if (lane == jl) scm |= (1 << slot);

        int t;
        GET_SLOT(r4c, slot, t);
        const int rc = __builtin_amdgcn_readlane(t, jl);
        if (rc < 0) {
          sink = jstar;
        } else {
          i = rc;
          // predict next column = current second-best of sh; prefetch its owner
          double b2 = INF;
          int    bj2 = 0x7fffffff;
          #pragma unroll
          for (int s = 0; s < NSLOT; ++s) {
            if ((vmask >> s) & 1) {
              if (!((scm >> s) & 1) && sh[s] < b2) {
                b2 = sh[s]; bj2 = lane + 64 * s;
              }
            }
          }
          const int src2 = argmin32_src(b2);
          const int j2 = __builtin_amdgcn_readlane(bj2, src2);
          int t2;
          GET_SLOT(r4c, (j2 >> 6), t2);
          const int rc2 = __builtin_amdgcn_readlane(t2, j2 & 63);
          if (rc2 >= 0 && rc2 != i) { pf_row = rc2; PRELOAD(rc2); }
          else pf_row = -1;
        }
      }

      #pragma unroll
      for (int s = 0; s < NSLOT; ++s)
        if ((vmask >> s) & 1) s_short[lane + 64 * s] = sh[s];
      __syncthreads();

      if (((srm0 >> lane) & 1ull) && lane != cur)
        u0 += minVal - s_short[s_col4row[lane]];
      const int r2 = lane + 64;
      if (((srm1 >> lane) & 1ull) && r2 != cur)
        u1 += minVal - s_short[s_col4row[r2]];
      if (lane == cur) u0 += minVal;
      if (r2 == cur)   u1 += minVal;
      #pragma unroll
      for (int s = 0; s < NSLOT; ++s)
        if ((scm >> s) & 1) vv[s] -= minVal - sh[s];
      __syncthreads();

      // augmenting-path flip
      int j = sink;
      while (true) {
        const int slot = j >> 6, src3 = j & 63;
        int t;
        GET_SLOT(pa, slot, t);
        const int i2 = __builtin_amdgcn_readlane(t, src3);
        if (lane == src3) SET_SLOT(r4c, slot, i2);
        const int nxt = s_col4row[i2];
        if (lane == 0) s_col4row[i2] = j;
        if (i2 == cur) break;
        j = nxt;
      }
      __syncthreads();

      {
        int n = -1;
        if (f0) n = __ffsll(f0) - 1; else if (f1) n = 64 + __ffsll(f1) - 1;
        if (n >= 0) { pf_row = n; PRELOAD(n); }
      }
    }
#undef PRELOAD

    // matched regression partials + CE delta gathers
    double l1 = 0.0, sl1 = 0.0, wid = 0.0;
    for (int i = lane; i < nv; i += 64) {
      const int r = s_col4row[i];
      const int c = s_vlab[i];
      wnll += dce[((size_t)b * NS + r) * 2 + (c - 1)];
      const float* ps = strokes + ((size_t)b * NS + r) * NP;
      const float* tp = tparams + ((size_t)b * NG + s_valid[i]) * NP;
      #pragma unroll
      for (int k = 0; k < 8; ++k) {
        const float d  = ps[k] - tp[k];
        const float ad = fabsf(d);
        l1 += (double)ad;
        const float sm = (ad < 0.1f) ? (0.5f * ad * ad / 0.1f) : (ad - 0.05f);
        sl1 += (double)sm;
      }
      const float d8 = fabsf(ps[8] - tp[8]);
      const float d9 = fabsf(ps[9] - tp[9]);
      wid += (double)d8 + (double)d9;
    }
    l1 = wave_sum(l1); sl1 = wave_sum(sl1); wid = wave_sum(wid);
    if (lane == 0) {
      atomicAdd(&acc[2], l1);
      atomicAdd(&acc[3], sl1);
      atomicAdd(&acc[4], wid);
      atomicAdd(&acc[5], (double)nv);
    }
  }

  wnll = wave_sum(wnll);
  if (lane == 0) {
    atomicAdd(&acc[0], wnll + baseCE[b]);
    atomicAdd(&acc[1], 30.0 + 0.9 * (double)nv);

    // last-block finalize (device-scope counter; coherent acc readback)
    __threadfence();
    const unsigned int done = atomicAdd(cnt, 1u);
    if (done == NB - 1) {
      __threadfence();
      const double a0 = atomicAdd(&acc[0], 0.0);
      const double a1 = atomicAdd(&acc[1], 0.0);
      const double a2 = atomicAdd(&acc[2], 0.0);
      const double a3 = atomicAdd(&acc[3], 0.0);
      const double a4 = atomicAdd(&acc[4], 0.0);
      const double a5 = atomicAdd(&acc[5], 0.0);
      const double denom = fmax(a5, 1.0);
      out[0] = (float)(a0 / a1 + 5.0 * (a2 + a3) / denom + 2.0 * a4 / denom);
    }
  }
}

// ---------------------------------------------------------------------------
// Fallback (ws too small): round-0 monolithic kernel (proven, absmax 0.0).
// ---------------------------------------------------------------------------
__global__ __launch_bounds__(64) void detr_match_loss_kernel(
    const float* __restrict__ strokes,
    const float* __restrict__ logits,
    const float* __restrict__ tparams,
    const int*   __restrict__ tlabels,
    double*      __restrict__ acc)
{
  __shared__ float  s_strokes[NS * NP];
  __shared__ float  s_probs[NS * 3];
  __shared__ float  s_vt[NG * NP];
  __shared__ int    s_valid[NG];
  __shared__ int    s_vlab[NG];
  __shared__ double s_u[NG];
  __shared__ int    s_col4row[NG];
  __shared__ int    s_SRb[NG];
  __shared__ double s_shortest[NS];
  __shared__ double s_v[NS];
  __shared__ int    s_path[NS];
  __shared__ int    s_SC[NS];
  __shared__ int    s_row4col[NS];
  __shared__ int    s_tc[NS];
  __shared__ int    s_nv;

  const int b    = blockIdx.x;
  const int lane = threadIdx.x;

  for (int idx = lane; idx < NS * NP; idx += 64)
    s_strokes[idx] = strokes[b * NS * NP + idx];

  for (int j = lane; j < NS; j += 64) {
    const float x0 = logits[(b * NS + j) * 3 + 0];
    const float x1 = logits[(b * NS + j) * 3 + 1];
    const float x2 = logits[(b * NS + j) * 3 + 2];
    const float m  = fmaxf(x0, fmaxf(x1, x2));
    const float e0 = expf(x0 - m), e1 = expf(x1 - m), e2 = expf(x2 - m);
    const float s  = e0 + e1 + e2;
    s_probs[j * 3 + 0] = e0 / s;
    s_probs[j * 3 + 1] = e1 / s;
    s_probs[j * 3 + 2] = e2 / s;
    s_tc[j]      = 0;
    s_row4col[j] = -1;
    s_v[j]       = 0.0;
  }

  if (lane == 0) {
    int nv = 0;
    for (int g = 0; g < NG; ++g) {
      const int lb = tlabels[b * NG + g];
      if (lb > 0) { s_valid[nv] = g; s_vlab[nv] = lb; ++nv; }
    }
    s_nv = nv;
  }
  __syncthreads();
  const int nv = s_nv;

  for (int idx = lane; idx < nv * NP; idx += 64) {
    const int i = idx / NP, k = idx % NP;
    s_vt[idx] = tparams[(b * NG + s_valid[i]) * NP + k];
  }
  for (int i = lane; i < nv; i += 64) { s_u[i] = 0.0; s_col4row[i] = -1; }
  __syncthreads();

  if (nv > 0) {
    for (int cur = 0; cur < nv; ++cur) {
      for (int j = lane; j < NS; j += 64) {
        s_shortest[j] = 1e300;
        s_path[j]     = -1;
        s_SC[j]       = 0;
      }
      for (int r = lane; r < nv; r += 64) s_SRb[r] = 0;
      __syncthreads();

      double minVal = 0.0;
      int i = cur;
      int sink = -1;

      while (sink == -1) {
        if (lane == 0) s_SRb[i] = 1;
        const double ui  = s_u[i];
        const int    cls = s_vlab[i];
        double vtr[NP];
        #pragma unroll
        for (int k = 0; k < NP; ++k) vtr[k] = (double)s_vt[i * NP + k];
        const double base = minVal - ui;

        double bestv = 1e300;
        int    bestj = 0x7fffffff;

        for (int j = lane; j < NS; j += 64) {
          if (!s_SC[j]) {
            const double p = (double)s_probs[j * 3 + cls];
            double a[NP];
            #pragma unroll
            for (int k = 0; k < NP; ++k)
              a[k] = fabs((double)s_strokes[j * NP + k] - vtr[k]);
            const double coord = ((a[0] + a[1]) + (a[2] + a[3])) +
                                 ((a[4] + a[5]) + (a[6] + a[7]));
            const double c = -p + 5.0 * coord + 2.0 * (a[8] + a[9]) +
                             2.0 * (a[0] + a[1]);
            const double d = base + c - s_v[j];
            if (d < s_shortest[j]) { s_shortest[j] = d; s_path[j] = i; }
            const double sv = s_shortest[j];
            if (sv < bestv) { bestv = sv; bestj = j; }
          }
        }

        #pragma unroll
        for (int off = 32; off > 0; off >>= 1) {
          const double ov = __shfl_xor(bestv, off);
          const int    oj = __shfl_xor(bestj, off);
          if (ov < bestv || (ov == bestv && oj < bestj)) { bestv = ov; bestj = oj; }
        }
        minVal = bestv;
        const int jstar = bestj;
        if (lane == 0) s_SC[jstar] = 1;
        __syncthreads();
        const int rc = s_row4col[jstar];
        if (rc < 0) sink = jstar; else i = rc;
      }

      for (int r = lane; r < nv; r += 64)
        if (s_SRb[r] && r != cur)
          s_u[r] += minVal - s_shortest[s_col4row[r]];
      if (lane == 0) s_u[cur] += minVal;
      for (int j = lane; j < NS; j += 64)
        if (s_SC[j]) s_v[j] -= minVal - s_shortest[j];
      __syncthreads();

      if (lane == 0) {
        int j = sink;
        while (true) {
          const int i2 = s_path[j];
          s_row4col[j] = i2;
          const int nxt = s_col4row[i2];
          s_col4row[i2] = j;
          if (i2 == cur) break;
          j = nxt;
        }
      }
      __syncthreads();
    }

    double l1 = 0.0, sl1 = 0.0, wid = 0.0;
    for (int i = lane; i < nv; i += 64) {
      const int r = s_col4row[i];
      s_tc[r] = s_vlab[i];
      #pragma unroll
      for (int k = 0; k < 8; ++k) {
        const float d  = s_strokes[r * NP + k] - s_vt[i * NP + k];
        const float ad = fabsf(d);
        l1 += (double)ad;
        const float s = (ad < 0.1f) ? (0.5f * ad * ad / 0.1f) : (ad - 0.05f);
        sl1 += (double)s;
      }
      const float d8 = fabsf(s_strokes[r * NP + 8] - s_vt[i * NP + 8]);
      const float d9 = fabsf(s_strokes[r * NP + 9] - s_vt[i * NP + 9]);
      wid += (double)d8 + (double)d9;
    }
    l1 = wave_sum(l1); sl1 = wave_sum(sl1); wid = wave_sum(wid);
    if (lane == 0) {
      atomicAdd(&acc[2], l1);
      atomicAdd(&acc[3], sl1);
      atomicAdd(&acc[4], wid);
      atomicAdd(&acc[5], (double)nv);
    }
  }
  __syncthreads();

  double wnll = 0.0, wsum = 0.0;
  for (int s = lane; s < NS; s += 64) {
    const int tc = s_tc[s];
    const double x0 = (double)logits[(b * NS + s) * 3 + 0];
    const double x1 = (double)logits[(b * NS + s) * 3 + 1];
    const double x2 = (double)logits[(b * NS + s) * 3 + 2];
    const double m   = fmax(x0, fmax(x1, x2));
    const double lse = log(exp(x0 - m) + exp(x1 - m) + exp(x2 - m));
    const double xt  = (tc == 0) ? x0 : ((tc == 1) ? x1 : x2);
    const double nll = -(xt - m - lse);
    const double w   = (tc == 0) ? 0.1 : 1.0;
    wnll += w * nll;
    wsum += w;
  }
  wnll = wave_sum(wnll); wsum = wave_sum(wsum);
  if (lane == 0) {
    atomicAdd(&acc[0], wnll);
    atomicAdd(&acc[1], wsum);
  }
}

__global__ void detr_finalize_kernel(const double* __restrict__ acc,
                                     float* __restrict__ out) {
  const double loss_ce = acc[0] / acc[1];
  const double denom   = fmax(acc[5], 1.0);
  const double loss = 1.0 * loss_ce
                    + 5.0 * (acc[2] + acc[3]) / denom
                    + 2.0 * acc[4] / denom;
  out[0] = (float)loss;
}

extern "C" void kernel_launch(void* const* d_in, const int* in_sizes, int n_in,
                              void* d_out, int out_size, void* d_ws, size_t ws_size,
                              hipStream_t stream) {
  const float* strokes = (const float*)d_in[0];
  const float* logits  = (const float*)d_in[1];
  const float* tparams = (const float*)d_in[2];
  const int*   tlabels = (const int*)d_in[3];
  char* ws = (char*)d_ws;
  double* acc = (double*)(ws + WS_ACC);

  if (ws_size >= WS_NEEDED) {
    double* rowmin = (double*)(ws + WS_ROWMIN);
    int*    rowarg = (int*)(ws + WS_ROWARG);
    double* dce    = (double*)(ws + WS_DCE);
    double* baseCE = (double*)(ws + WS_BASECE);
    double* C      = (double*)(ws + WS_C);
    unsigned int* cnt = (unsigned int*)(ws + 48);

    detr_cost_kernel<<<dim3(NB, 10), 256, 0, stream>>>(
        strokes, logits, tparams, tlabels, C, dce, baseCE, rowmin, rowarg, acc);
    detr_match_fast_kernel<<<NB, 64, 0, stream>>>(
        strokes, tparams, tlabels, C, rowmin, rowarg, dce, baseCE, acc, cnt,
        (float*)d_out);
  } else {
    hipMemsetAsync(d_ws, 0, 64, stream);
    detr_match_loss_kernel<<<NB, 64, 0, stream>>>(strokes, logits, tparams,
                                                  tlabels, acc);
    detr_finalize_kernel<<<1, 1, 0, stream>>>(acc, (float*)d_out);
  }
}

// Round 12
// 57.681 us; speedup vs baseline: 1.3499x; 1.1622x over previous
//
#include <hip/hip_runtime.h>
#include <math.h>
#include <stdint.h>

#define NB 128
#define NS 300   // pred slots (columns)
#define NG 100   // gt slots (max rows)
#define NP 10    // params per stroke
#define NSLOT 5  // ceil(NS/64)

// ws layout (all 8-aligned):
#define WS_ACC     0                         // 6 doubles + counter @48 (64 B)
#define WS_ROWMIN  1024                      // NB*NG*8 = 102400
#define WS_ROWARG  103424                    // NB*NG*4 = 51200
#define WS_DCE     154624                    // NB*NS*2*8 = 614400
#define WS_BASECE  769024                    // NB*8 (pad to 1024)
#define WS_C       770048                    // NB*NG*NS*8 = 30720000
#define WS_NEEDED  (WS_C + (size_t)NB * NG * NS * 8)

#define GET_SLOT(arr, slot, out) do { switch (slot) { \
  case 0: out = arr[0]; break; case 1: out = arr[1]; break; \
  case 2: out = arr[2]; break; case 3: out = arr[3]; break; \
  default: out = arr[4]; break; } } while (0)
#define SET_SLOT(arr, slot, val) do { switch (slot) { \
  case 0: arr[0] = val; break; case 1: arr[1] = val; break; \
  case 2: arr[2] = val; break; case 3: arr[3] = val; break; \
  default: arr[4] = val; break; } } while (0)

__device__ __forceinline__ double wave_sum(double v) {
  #pragma unroll
  for (int off = 32; off > 0; off >>= 1) v += __shfl_xor(v, off);
  return v;
}

// ---- order-preserving f64 <-> u64 key ----
__device__ __forceinline__ uint64_t pack_key(double d) {
  const uint64_t b = (uint64_t)__double_as_longlong(d);
  return (b >> 63) ? ~b : (b | 0x8000000000000000ull);
}
__device__ __forceinline__ double unpack_key(uint64_t k) {
  const uint64_t b = (k >> 63) ? (k & 0x7fffffffffffffffull) : ~k;
  return __longlong_as_double((long long)b);
}

__device__ __forceinline__ double rl_f64(double v, int src) {
  const uint64_t b = (uint64_t)__double_as_longlong(v);
  const int lo = __builtin_amdgcn_readlane((int)(uint32_t)b, src);
  const int hi = __builtin_amdgcn_readlane((int)(uint32_t)(b >> 32), src);
  return __longlong_as_double((long long)(((uint64_t)(uint32_t)hi << 32) |
                                          (uint32_t)lo));
}

template <int CTRL>
__device__ __forceinline__ uint64_t dpp_u64_or_max(uint64_t x) {
  const int lo = (int)(uint32_t)x;
  const int hi = (int)(uint32_t)(x >> 32);
  const int lo2 = __builtin_amdgcn_update_dpp(-1, lo, CTRL, 0xF, 0xF, false);
  const int hi2 = __builtin_amdgcn_update_dpp(-1, hi, CTRL, 0xF, 0xF, false);
  return ((uint64_t)(uint32_t)hi2 << 32) | (uint32_t)lo2;
}

__device__ __forceinline__ void wave_argmin(uint64_t key, int bestj,
                                            double& minVal, int& jstar) {
  uint64_t k = key;
  { const uint64_t o = dpp_u64_or_max<0x111>(k); if (o < k) k = o; }
  { const uint64_t o = dpp_u64_or_max<0x112>(k); if (o < k) k = o; }
  { const uint64_t o = dpp_u64_or_max<0x114>(k); if (o < k) k = o; }
  { const uint64_t o = dpp_u64_or_max<0x118>(k); if (o < k) k = o; }
  { const uint64_t o = dpp_u64_or_max<0x142>(k); if (o < k) k = o; }
  { const uint64_t o = dpp_u64_or_max<0x143>(k); if (o < k) k = o; }
  const uint32_t mlo = (uint32_t)__builtin_amdgcn_readlane((int)(uint32_t)k, 63);
  const uint32_t mhi = (uint32_t)__builtin_amdgcn_readlane((int)(uint32_t)(k >> 32), 63);
  const uint64_t minkey = ((uint64_t)mhi << 32) | mlo;
  const unsigned long long winners = __ballot(key == minkey);
  const int src = __ffsll(winners) - 1;
  jstar = __builtin_amdgcn_readlane(bestj, src);
  minVal = unpack_key(minkey);
}

// ---- fast 32-bit-high-word DPP argmin with exact tie resolution ----
__device__ __forceinline__ int argmin32_src(double bestv) {
  const uint64_t key = pack_key(bestv);
  const uint32_t hi = (uint32_t)(key >> 32);
  int x = (int)hi;
  { const int o = __builtin_amdgcn_update_dpp(-1, x, 0x111, 0xF, 0xF, false);
    x = ((uint32_t)o < (uint32_t)x) ? o : x; }
  { const int o = __builtin_amdgcn_update_dpp(-1, x, 0x112, 0xF, 0xF, false);
    x = ((uint32_t)o < (uint32_t)x) ? o : x; }
  { const int o = __builtin_amdgcn_update_dpp(-1, x, 0x114, 0xF, 0xF, false);
    x = ((uint32_t)o < (uint32_t)x) ? o : x; }
  { const int o = __builtin_amdgcn_update_dpp(-1, x, 0x118, 0xF, 0xF, false);
    x = ((uint32_t)o < (uint32_t)x) ? o : x; }
  { const int o = __builtin_amdgcn_update_dpp(-1, x, 0x142, 0xF, 0xF, false);
    x = ((uint32_t)o < (uint32_t)x) ? o : x; }
  { const int o = __builtin_amdgcn_update_dpp(-1, x, 0x143, 0xF, 0xF, false);
    x = ((uint32_t)o < (uint32_t)x) ? o : x; }
  const uint32_t minhi = (uint32_t)__builtin_amdgcn_readlane(x, 63);
  unsigned long long cand = __ballot(hi == minhi);
  int src = __ffsll(cand) - 1;
  if (__popcll(cand) > 1) {
    uint64_t bk = ~0ull; int bs = src;
    while (cand) {
      const int l = __ffsll(cand) - 1; cand &= cand - 1;
      const uint32_t klo = (uint32_t)__builtin_amdgcn_readlane((int)(uint32_t)key, l);
      const uint32_t khi = (uint32_t)__builtin_amdgcn_readlane((int)(uint32_t)(key >> 32), l);
      const uint64_t kk = ((uint64_t)khi << 32) | klo;
      if (kk < bk) { bk = kk; bs = l; }
    }
    src = bs;
  }
  return src;
}

// ---------------------------------------------------------------------------
// Kernel B: cost matrix C (f64, bitwise == numpy) + fused row minima + CE
// decomposition (cb==0) + acc/counter zero-init (block 0,0).
// ---------------------------------------------------------------------------
__global__ __launch_bounds__(256) void detr_cost_kernel(
    const float* __restrict__ strokes,
    const float* __restrict__ logits,
    const float* __restrict__ tparams,
    const int*   __restrict__ tlabels,
    double*      __restrict__ C,
    double*      __restrict__ dce,
    double*      __restrict__ baseCE,
    double*      __restrict__ rowmin,
    int*         __restrict__ rowarg,
    double*      __restrict__ acc)
{
  __shared__ float  sS[NS * NP];
  __shared__ float  sP[NS * 3];
  __shared__ float  sVT[10 * NP];
  __shared__ int    sCls[10];
  __shared__ int    s_valid[NG];
  __shared__ int    s_vlab[NG];
  __shared__ int    s_nv;
  __shared__ double s_bp[4];
  __shared__ double sC[10 * NS];

  const int b   = blockIdx.x;
  const int cb  = blockIdx.y;
  const int tid = threadIdx.x;

  if (b == 0 && cb == 0 && tid < 8)
    acc[tid] = 0.0;   // zeroes 6 accumulators + the completion counter @48

  for (int idx = tid; idx < NS * NP; idx += 256)
    sS[idx] = strokes[b * NS * NP + idx];

  for (int j = tid; j < NS; j += 256) {
    const float x0 = logits[(b * NS + j) * 3 + 0];
    const float x1 = logits[(b * NS + j) * 3 + 1];
    const float x2 = logits[(b * NS + j) * 3 + 2];
    const float m  = fmaxf(x0, fmaxf(x1, x2));
    const float e0 = expf(x0 - m), e1 = expf(x1 - m), e2 = expf(x2 - m);
    const float s  = e0 + e1 + e2;
    sP[j * 3 + 0] = e0 / s;
    sP[j * 3 + 1] = e1 / s;
    sP[j * 3 + 2] = e2 / s;
  }

  if (tid < 64) {
    const unsigned long long below = (1ull << tid) - 1ull;
    const int lb1 = tlabels[b * NG + tid];
    const bool in2 = tid < (NG - 64);
    const int lb2 = in2 ? tlabels[b * NG + 64 + tid] : 0;
    const unsigned long long m1 = __ballot(lb1 > 0);
    const unsigned long long m2 = __ballot(in2 && lb2 > 0);
    const int c1 = __popcll(m1);
    if (lb1 > 0) {
      const int p = __popcll(m1 & below);
      s_valid[p] = tid; s_vlab[p] = lb1;
    }
    if (in2 && lb2 > 0) {
      const int p = c1 + __popcll(m2 & below);
      s_valid[p] = 64 + tid; s_vlab[p] = lb2;
    }
    if (tid == 0) s_nv = c1 + __popcll(m2);
  }
  __syncthreads();

  if (cb == 0) {
    double bsum = 0.0;
    for (int s = tid; s < NS; s += 256) {
      const double x0 = (double)logits[(b * NS + s) * 3 + 0];
      const double x1 = (double)logits[(b * NS + s) * 3 + 1];
      const double x2 = (double)logits[(b * NS + s) * 3 + 2];
      const double m   = fmax(x0, fmax(x1, x2));
      const double lse = log(exp(x0 - m) + exp(x1 - m) + exp(x2 - m));
      const double nll0 = -(x0 - m - lse);
      const double nll1 = -(x1 - m - lse);
      const double nll2 = -(x2 - m - lse);
      dce[((size_t)b * NS + s) * 2 + 0] = nll1 - 0.1 * nll0;
      dce[((size_t)b * NS + s) * 2 + 1] = nll2 - 0.1 * nll0;
      bsum += 0.1 * nll0;
    }
    bsum = wave_sum(bsum);
    if ((tid & 63) == 0) s_bp[tid >> 6] = bsum;
    __syncthreads();
    if (tid == 0) baseCE[b] = (s_bp[0] + s_bp[1]) + (s_bp[2] + s_bp[3]);
  }

  const int nv = s_nv;
  const int i0 = cb * 10;
  const int nrow = (nv - i0 < 10) ? (nv - i0) : 10;
  if (nrow <= 0) return;

  for (int idx = tid; idx < nrow * NP; idx += 256) {
    const int il = idx / NP, k = idx % NP;
    sVT[il * NP + k] = tparams[(b * NG + s_valid[i0 + il]) * NP + k];
  }
  if (tid < nrow) sCls[tid] = s_vlab[i0 + tid];
  __syncthreads();

  for (int e = tid; e < nrow * NS; e += 256) {
    const int il = e / NS, j = e - il * NS;
    const int cls = sCls[il];
    const double p = (double)sP[j * 3 + cls];
    double a[NP];
    #pragma unroll
    for (int k = 0; k < NP; ++k)
      a[k] = fabs((double)sS[j * NP + k] - (double)sVT[il * NP + k]);
    const double coord = ((a[0] + a[1]) + (a[2] + a[3])) +
                         ((a[4] + a[5]) + (a[6] + a[7]));
    const double c = -p + 5.0 * coord + 2.0 * (a[8] + a[9]) +
                     2.0 * (a[0] + a[1]);
    C[((size_t)b * NG + (i0 + il)) * NS + j] = c;
    sC[il * NS + j] = c;
  }
  __syncthreads();

  // fused row minima: wave w reduces rows w, w+4, ...
  const int wid  = tid >> 6;
  const int lane = tid & 63;
  const int vmask = (lane < NS - 4 * 64) ? 0x1F : 0x0F;
  for (int row = wid; row < nrow; row += 4) {
    double bestv = (double)INFINITY;
    int    bestj = 0x7fffffff;
    #pragma unroll
    for (int s = 0; s < NSLOT; ++s) {
      if ((vmask >> s) & 1) {
        const double c = sC[row * NS + lane + 64 * s];
        if (c < bestv) { bestv = c; bestj = lane + 64 * s; }
      }
    }
    double mv; int js;
    wave_argmin(pack_key(bestv), bestj, mv, js);
    if (lane == 0) {
      rowmin[b * NG + i0 + row] = mv;
      rowarg[b * NG + i0 + row] = js;
    }
  }
}

// ---------------------------------------------------------------------------
// Kernel C: JV LAP — warm start + greedy tight claims + SAP with 32-bit DPP
// argmin + DETERMINISTIC next-row prefetch (rc is known exactly once the
// argmin resolves; the old speculative second-best prediction cost ~150cy of
// argmin on the chain every step to sometimes save a load); fused loss
// epilogue; last-block finalize.
// ---------------------------------------------------------------------------
__global__ __launch_bounds__(64) void detr_match_fast_kernel(
    const float*  __restrict__ strokes,
    const float*  __restrict__ tparams,
    const int*    __restrict__ tlabels,
    const double* __restrict__ C,
    const double* __restrict__ rowmin,
    const int*    __restrict__ rowarg,
    const double* __restrict__ dce,
    const double* __restrict__ baseCE,
    double*       __restrict__ acc,
    unsigned int* __restrict__ cnt,
    float*        __restrict__ out)
{
  __shared__ int    s_valid[NG];
  __shared__ int    s_vlab[NG];
  __shared__ int    s_col4row[NG];
  __shared__ int    s_claimC[NS];
  __shared__ int    s_r4cL[NS];
  __shared__ double s_short[NS];

  const int b    = blockIdx.x;
  const int lane = threadIdx.x;

  for (int j = lane; j < NS; j += 64) {
    s_claimC[j] = 0x7fffffff; s_r4cL[j] = -1;
  }

  const unsigned long long below = (1ull << lane) - 1ull;
  const int lb1 = tlabels[b * NG + lane];
  const bool in2 = lane < (NG - 64);
  const int lb2 = in2 ? tlabels[b * NG + 64 + lane] : 0;
  const unsigned long long m1 = __ballot(lb1 > 0);
  const unsigned long long m2 = __ballot(in2 && lb2 > 0);
  const int c1 = __popcll(m1);
  if (lb1 > 0) {
    const int p = __popcll(m1 & below);
    s_valid[p] = lane; s_vlab[p] = lb1;
  }
  if (in2 && lb2 > 0) {
    const int p = c1 + __popcll(m2 & below);
    s_valid[p] = 64 + lane; s_vlab[p] = lb2;
  }
  const int nv = c1 + __popcll(m2);

  for (int i = lane; i < nv; i += 64) s_col4row[i] = -1;
  __syncthreads();

  double wnll = 0.0;

  if (nv > 0) {
    const double* Cb = C + (size_t)b * NG * NS;
    const double INF = (double)INFINITY;
    const int vmask = (lane < NS - 4 * 64) ? 0x1F : 0x0F;

    double rm0 = 0.0, rm1 = 0.0;
    int    ra0 = -1,  ra1 = -1;
    if (lane < nv) {
      rm0 = rowmin[b * NG + lane];
      ra0 = rowarg[b * NG + lane];
    }
    if (lane + 64 < nv) {
      rm1 = rowmin[b * NG + lane + 64];
      ra1 = rowarg[b * NG + lane + 64];
    }

    if (lane < nv)      atomicMin(&s_claimC[ra0], lane);
    if (lane + 64 < nv) atomicMin(&s_claimC[ra1], lane + 64);
    __syncthreads();
    if (lane < nv && s_claimC[ra0] == lane) {
      s_r4cL[ra0] = lane; s_col4row[lane] = ra0;
    }
    if (lane + 64 < nv && s_claimC[ra1] == lane + 64) {
      s_r4cL[ra1] = lane + 64; s_col4row[lane + 64] = ra1;
    }
    __syncthreads();

    int r4c[NSLOT];
    #pragma unroll
    for (int s = 0; s < NSLOT; ++s)
      r4c[s] = ((vmask >> s) & 1) ? s_r4cL[lane + 64 * s] : -1;
    double vv[NSLOT];
    #pragma unroll
    for (int s = 0; s < NSLOT; ++s) vv[s] = 0.0;

    double u0 = rm0, u1 = rm1;

    unsigned long long f0 = __ballot(lane < nv && s_col4row[lane] < 0);
    unsigned long long f1 = __ballot(lane + 64 < nv && s_col4row[lane + 64] < 0);

    int pf_row = -1;
    double pfv[NSLOT];
    #pragma unroll
    for (int s = 0; s < NSLOT; ++s) pfv[s] = 0.0;

#define PRELOAD(ROW) do { \
      const double* Pr_ = Cb + (size_t)(ROW) * NS; \
      pfv[0] = Pr_[lane]; \
      pfv[1] = Pr_[lane + 64]; \
      pfv[2] = Pr_[lane + 128]; \
      pfv[3] = Pr_[lane + 192]; \
      if (lane < NS - 256) pfv[4] = Pr_[lane + 256]; \
    } while (0)

    {
      int n = -1;
      if (f0) n = __ffsll(f0) - 1; else if (f1) n = 64 + __ffsll(f1) - 1;
      if (n >= 0) { pf_row = n; PRELOAD(n); }
    }

    while (f0 | f1) {
      int cur;
      if (f0) { cur = __ffsll(f0) - 1; f0 &= f0 - 1; }
      else    { cur = 64 + __ffsll(f1) - 1; f1 &= f1 - 1; }

      double sh[NSLOT];
      int    pa[NSLOT];
      #pragma unroll
      for (int s = 0; s < NSLOT; ++s) { sh[s] = INF; pa[s] = -1; }
      int scm = 0;
      unsigned long long srm0 = 0ull, srm1 = 0ull;
      double minVal = 0.0;
      int i = cur;
      int sink = -1;

      while (sink == -1) {
        if (i < 64) srm0 |= (1ull << i); else srm1 |= (1ull << (i - 64));
        const double ucur = (i < 64) ? rl_f64(u0, i) : rl_f64(u1, i - 64);
        const double base = minVal - ucur;

        double cv[NSLOT];
        if (i == pf_row) {
          #pragma unroll
          for (int s = 0; s < NSLOT; ++s) cv[s] = pfv[s];
        } else {
          const double* Gr = Cb + (size_t)i * NS;
          #pragma unroll
          for (int s = 0; s < NSLOT; ++s)
            if ((vmask >> s) & 1) cv[s] = Gr[lane + 64 * s];
        }

        double bestv = INF;
        int    bestj = 0x7fffffff;
        #pragma unroll
        for (int s = 0; s < NSLOT; ++s) {
          if ((vmask >> s) & 1) {
            if (!((scm >> s) & 1)) {
              const double dd = base + cv[s] - vv[s];
              if (dd < sh[s]) { sh[s] = dd; pa[s] = i; }
              if (sh[s] < bestv) { bestv = sh[s]; bestj = lane + 64 * s; }
            }
          }
        }

        const int src = argmin32_src(bestv);
        const int jstar = __builtin_amdgcn_readlane(bestj, src);
        minVal = rl_f64(bestv, src);
        const int slot = jstar >> 6;
        const int jl   = jstar & 63;
        if (lane == jl) scm |= (1 << slot);

        int t;
        GET_SLOT(r4c, slot, t);
        const int rc = __builtin_amdgcn_readlane(t, jl);
        if (rc < 0) {
          sink = jstar;
        } else {
          // deterministic: the next row IS rc — issue its load right now,
          // ~150cy earlier than loop-top, with zero prediction work.
          i = rc;
          pf_row = rc;
          PRELOAD(rc);
        }
      }

      #pragma unroll
      for (int s = 0; s < NSLOT; ++s)
        if ((vmask >> s) & 1) s_short[lane + 64 * s] = sh[s];
      __syncthreads();

      if (((srm0 >> lane) & 1ull) && lane != cur)
        u0 += minVal - s_short[s_col4row[lane]];
      const int r2 = lane + 64;
      if (((srm1 >> lane) & 1ull) && r2 != cur)
        u1 += minVal - s_short[s_col4row[r2]];
      if (lane == cur) u0 += minVal;
      if (r2 == cur)   u1 += minVal;
      #pragma unroll
      for (int s = 0; s < NSLOT; ++s)
        if ((scm >> s) & 1) vv[s] -= minVal - sh[s];
      __syncthreads();

      // augmenting-path flip
      int j = sink;
      while (true) {
        const int slot = j >> 6, src3 = j & 63;
        int t;
        GET_SLOT(pa, slot, t);
        const int i2 = __builtin_amdgcn_readlane(t, src3);
        if (lane == src3) SET_SLOT(r4c, slot, i2);
        const int nxt = s_col4row[i2];
        if (lane == 0) s_col4row[i2] = j;
        if (i2 == cur) break;
        j = nxt;
      }
      __syncthreads();

      {
        int n = -1;
        if (f0) n = __ffsll(f0) - 1; else if (f1) n = 64 + __ffsll(f1) - 1;
        if (n >= 0) { pf_row = n; PRELOAD(n); }
      }
    }
#undef PRELOAD

    // matched regression partials + CE delta gathers
    double l1 = 0.0, sl1 = 0.0, wid = 0.0;
    for (int i = lane; i < nv; i += 64) {
      const int r = s_col4row[i];
      const int c = s_vlab[i];
      wnll += dce[((size_t)b * NS + r) * 2 + (c - 1)];
      const float* ps = strokes + ((size_t)b * NS + r) * NP;
      const float* tp = tparams + ((size_t)b * NG + s_valid[i]) * NP;
      #pragma unroll
      for (int k = 0; k < 8; ++k) {
        const float d  = ps[k] - tp[k];
        const float ad = fabsf(d);
        l1 += (double)ad;
        const float sm = (ad < 0.1f) ? (0.5f * ad * ad / 0.1f) : (ad - 0.05f);
        sl1 += (double)sm;
      }
      const float d8 = fabsf(ps[8] - tp[8]);
      const float d9 = fabsf(ps[9] - tp[9]);
      wid += (double)d8 + (double)d9;
    }
    l1 = wave_sum(l1); sl1 = wave_sum(sl1); wid = wave_sum(wid);
    if (lane == 0) {
      atomicAdd(&acc[2], l1);
      atomicAdd(&acc[3], sl1);
      atomicAdd(&acc[4], wid);
      atomicAdd(&acc[5], (double)nv);
    }
  }

  wnll = wave_sum(wnll);
  if (lane == 0) {
    atomicAdd(&acc[0], wnll + baseCE[b]);
    atomicAdd(&acc[1], 30.0 + 0.9 * (double)nv);

    // last-block finalize (device-scope counter; coherent acc readback)
    __threadfence();
    const unsigned int done = atomicAdd(cnt, 1u);
    if (done == NB - 1) {
      __threadfence();
      const double a0 = atomicAdd(&acc[0], 0.0);
      const double a1 = atomicAdd(&acc[1], 0.0);
      const double a2 = atomicAdd(&acc[2], 0.0);
      const double a3 = atomicAdd(&acc[3], 0.0);
      const double a4 = atomicAdd(&acc[4], 0.0);
      const double a5 = atomicAdd(&acc[5], 0.0);
      const double denom = fmax(a5, 1.0);
      out[0] = (float)(a0 / a1 + 5.0 * (a2 + a3) / denom + 2.0 * a4 / denom);
    }
  }
}

// ---------------------------------------------------------------------------
// Fallback (ws too small): round-0 monolithic kernel (proven, absmax 0.0).
// ---------------------------------------------------------------------------
__global__ __launch_bounds__(64) void detr_match_loss_kernel(
    const float* __restrict__ strokes,
    const float* __restrict__ logits,
    const float* __restrict__ tparams,
    const int*   __restrict__ tlabels,
    double*      __restrict__ acc)
{
  __shared__ float  s_strokes[NS * NP];
  __shared__ float  s_probs[NS * 3];
  __shared__ float  s_vt[NG * NP];
  __shared__ int    s_valid[NG];
  __shared__ int    s_vlab[NG];
  __shared__ double s_u[NG];
  __shared__ int    s_col4row[NG];
  __shared__ int    s_SRb[NG];
  __shared__ double s_shortest[NS];
  __shared__ double s_v[NS];
  __shared__ int    s_path[NS];
  __shared__ int    s_SC[NS];
  __shared__ int    s_row4col[NS];
  __shared__ int    s_tc[NS];
  __shared__ int    s_nv;

  const int b    = blockIdx.x;
  const int lane = threadIdx.x;

  for (int idx = lane; idx < NS * NP; idx += 64)
    s_strokes[idx] = strokes[b * NS * NP + idx];

  for (int j = lane; j < NS; j += 64) {
    const float x0 = logits[(b * NS + j) * 3 + 0];
    const float x1 = logits[(b * NS + j) * 3 + 1];
    const float x2 = logits[(b * NS + j) * 3 + 2];
    const float m  = fmaxf(x0, fmaxf(x1, x2));
    const float e0 = expf(x0 - m), e1 = expf(x1 - m), e2 = expf(x2 - m);
    const float s  = e0 + e1 + e2;
    s_probs[j * 3 + 0] = e0 / s;
    s_probs[j * 3 + 1] = e1 / s;
    s_probs[j * 3 + 2] = e2 / s;
    s_tc[j]      = 0;
    s_row4col[j] = -1;
    s_v[j]       = 0.0;
  }

  if (lane == 0) {
    int nv = 0;
    for (int g = 0; g < NG; ++g) {
      const int lb = tlabels[b * NG + g];
      if (lb > 0) { s_valid[nv] = g; s_vlab[nv] = lb; ++nv; }
    }
    s_nv = nv;
  }
  __syncthreads();
  const int nv = s_nv;

  for (int idx = lane; idx < nv * NP; idx += 64) {
    const int i = idx / NP, k = idx % NP;
    s_vt[idx] = tparams[(b * NG + s_valid[i]) * NP + k];
  }
  for (int i = lane; i < nv; i += 64) { s_u[i] = 0.0; s_col4row[i] = -1; }
  __syncthreads();

  if (nv > 0) {
    for (int cur = 0; cur < nv; ++cur) {
      for (int j = lane; j < NS; j += 64) {
        s_shortest[j] = 1e300;
        s_path[j]     = -1;
        s_SC[j]       = 0;
      }
      for (int r = lane; r < nv; r += 64) s_SRb[r] = 0;
      __syncthreads();

      double minVal = 0.0;
      int i = cur;
      int sink = -1;

      while (sink == -1) {
        if (lane == 0) s_SRb[i] = 1;
        const double ui  = s_u[i];
        const int    cls = s_vlab[i];
        double vtr[NP];
        #pragma unroll
        for (int k = 0; k < NP; ++k) vtr[k] = (double)s_vt[i * NP + k];
        const double base = minVal - ui;

        double bestv = 1e300;
        int    bestj = 0x7fffffff;

        for (int j = lane; j < NS; j += 64) {
          if (!s_SC[j]) {
            const double p = (double)s_probs[j * 3 + cls];
            double a[NP];
            #pragma unroll
            for (int k = 0; k < NP; ++k)
              a[k] = fabs((double)s_strokes[j * NP + k] - vtr[k]);
            const double coord = ((a[0] + a[1]) + (a[2] + a[3])) +
                                 ((a[4] + a[5]) + (a[6] + a[7]));
            const double c = -p + 5.0 * coord + 2.0 * (a[8] + a[9]) +
                             2.0 * (a[0] + a[1]);
            const double d = base + c - s_v[j];
            if (d < s_shortest[j]) { s_shortest[j] = d; s_path[j] = i; }
            const double sv = s_shortest[j];
            if (sv < bestv) { bestv = sv; bestj = j; }
          }
        }

        #pragma unroll
        for (int off = 32; off > 0; off >>= 1) {
          const double ov = __shfl_xor(bestv, off);
          const int    oj = __shfl_xor(bestj, off);
          if (ov < bestv || (ov == bestv && oj < bestj)) { bestv = ov; bestj = oj; }
        }
        minVal = bestv;
        const int jstar = bestj;
        if (lane == 0) s_SC[jstar] = 1;
        __syncthreads();
        const int rc = s_row4col[jstar];
        if (rc < 0) sink = jstar; else i = rc;
      }

      for (int r = lane; r < nv; r += 64)
        if (s_SRb[r] && r != cur)
          s_u[r] += minVal - s_shortest[s_col4row[r]];
      if (lane == 0) s_u[cur] += minVal;
      for (int j = lane; j < NS; j += 64)
        if (s_SC[j]) s_v[j] -= minVal - s_shortest[j];
      __syncthreads();

      if (lane == 0) {
        int j = sink;
        while (true) {
          const int i2 = s_path[j];
          s_row4col[j] = i2;
          const int nxt = s_col4row[i2];
          s_col4row[i2] = j;
          if (i2 == cur) break;
          j = nxt;
        }
      }
      __syncthreads();
    }

    double l1 = 0.0, sl1 = 0.0, wid = 0.0;
    for (int i = lane; i < nv; i += 64) {
      const int r = s_col4row[i];
      s_tc[r] = s_vlab[i];
      #pragma unroll
      for (int k = 0; k < 8; ++k) {
        const float d  = s_strokes[r * NP + k] - s_vt[i * NP + k];
        const float ad = fabsf(d);
        l1 += (double)ad;
        const float s = (ad < 0.1f) ? (0.5f * ad * ad / 0.1f) : (ad - 0.05f);
        sl1 += (double)s;
      }
      const float d8 = fabsf(s_strokes[r * NP + 8] - s_vt[i * NP + 8]);
      const float d9 = fabsf(s_strokes[r * NP + 9] - s_vt[i * NP + 9]);
      wid += (double)d8 + (double)d9;
    }
    l1 = wave_sum(l1); sl1 = wave_sum(sl1); wid = wave_sum(wid);
    if (lane == 0) {
      atomicAdd(&acc[2], l1);
      atomicAdd(&acc[3], sl1);
      atomicAdd(&acc[4], wid);
      atomicAdd(&acc[5], (double)nv);
    }
  }
  __syncthreads();

  double wnll = 0.0, wsum = 0.0;
  for (int s = lane; s < NS; s += 64) {
    const int tc = s_tc[s];
    const double x0 = (double)logits[(b * NS + s) * 3 + 0];
    const double x1 = (double)logits[(b * NS + s) * 3 + 1];
    const double x2 = (double)logits[(b * NS + s) * 3 + 2];
    const double m   = fmax(x0, fmax(x1, x2));
    const double lse = log(exp(x0 - m) + exp(x1 - m) + exp(x2 - m));
    const double xt  = (tc == 0) ? x0 : ((tc == 1) ? x1 : x2);
    const double nll = -(xt - m - lse);
    const double w   = (tc == 0) ? 0.1 : 1.0;
    wnll += w * nll;
    wsum += w;
  }
  wnll = wave_sum(wnll); wsum = wave_sum(wsum);
  if (lane == 0) {
    atomicAdd(&acc[0], wnll);
    atomicAdd(&acc[1], wsum);
  }
}

__global__ void detr_finalize_kernel(const double* __restrict__ acc,
                                     float* __restrict__ out) {
  const double loss_ce = acc[0] / acc[1];
  const double denom   = fmax(acc[5], 1.0);
  const double loss = 1.0 * loss_ce
                    + 5.0 * (acc[2] + acc[3]) / denom
                    + 2.0 * acc[4] / denom;
  out[0] = (float)loss;
}

extern "C" void kernel_launch(void* const* d_in, const int* in_sizes, int n_in,
                              void* d_out, int out_size, void* d_ws, size_t ws_size,
                              hipStream_t stream) {
  const float* strokes = (const float*)d_in[0];
  const float* logits  = (const float*)d_in[1];
  const float* tparams = (const float*)d_in[2];
  const int*   tlabels = (const int*)d_in[3];
  char* ws = (char*)d_ws;
  double* acc = (double*)(ws + WS_ACC);

  if (ws_size >= WS_NEEDED) {
    double* rowmin = (double*)(ws + WS_ROWMIN);
    int*    rowarg = (int*)(ws + WS_ROWARG);
    double* dce    = (double*)(ws + WS_DCE);
    double* baseCE = (double*)(ws + WS_BASECE);
    double* C      = (double*)(ws + WS_C);
    unsigned int* cnt = (unsigned int*)(ws + 48);

    detr_cost_kernel<<<dim3(NB, 10), 256, 0, stream>>>(
        strokes, logits, tparams, tlabels, C, dce, baseCE, rowmin, rowarg, acc);
    detr_match_fast_kernel<<<NB, 64, 0, stream>>>(
        strokes, tparams, tlabels, C, rowmin, rowarg, dce, baseCE, acc, cnt,
        (float*)d_out);
  } else {
    hipMemsetAsync(d_ws, 0, 64, stream);
    detr_match_loss_kernel<<<NB, 64, 0, stream>>>(strokes, logits, tparams,
                                                  tlabels, acc);
    detr_finalize_kernel<<<1, 1, 0, stream>>>(acc, (float*)d_out);
  }
}